// Round 6
// baseline (222.328 us; speedup 1.0000x reference)
//
#include <hip/hip_runtime.h>
#include <math.h>

#define NTOT 262144   // total nodes
#define BG   64       // graphs
#define NNPG 4096     // nodes per graph
#define ET   1048576  // directed edges
#define EPG  16384    // edges per graph
#define HD   128
#define LD   64
#define NSEG 129
#define SLOTPG 28672  // max padded slots per graph (EPG + 3*NNPG)
#define SLOTCAP (BG*SLOTPG)
#define TN   128      // nodes per agg tile
#define SCAP 1152     // staged slots per tile (fallback to global past this)

// ======== fused CSR build (1 block/graph, LDS atomics) + tab1 (block 64) ====
// tab1: relu(a*w1[j]+b1[j]): kind 0: w>0, kind 1: w<0, kind 2: w==0 (act iff b>0).
// Incremental: segment s->s+1 flips exactly the unit with rank s.
// AC float layout: s*256 + (k>>2)*8 + (k&3), +4 for C  (per (s,lane) 32B pair)
__global__ void __launch_bounds__(1024) k_csr(
    const int* __restrict__ ei, const float* __restrict__ x,
    const float* __restrict__ w1, const float* __restrict__ b1,
    const float* __restrict__ w2,
    int* __restrict__ cnt, int* __restrict__ off, int* __restrict__ csrc,
    float2* __restrict__ xd,
    float* __restrict__ t1, float* __restrict__ AC1, int* __restrict__ nfp)
{
  __shared__ union {
    struct { int cnt[NNPG]; int tsum[1024]; } c;
    struct { float w2s[HD*HD]; float ts[128], ws[128], bs[128]; int ks[128], jr[128]; } t;
  } u;
  int tid = threadIdx.x;

  if (blockIdx.x == BG){
    // ---------------- tab1 ----------------
    {
      const float4* src = (const float4*)w2;
      float4* dst = (float4*)u.t.w2s;
      for (int idx = tid; idx < HD*HD/4; idx += 1024) dst[idx] = src[idx];
    }
    if (tid < 128){
      float w = w1[tid], b = b1[tid];
      float t; int kind;
      if (w != 0.0f){ t = -b / w; kind = (w > 0.0f) ? 0 : 1; }
      else          { t = INFINITY; kind = 2; }
      u.t.ts[tid] = t; u.t.ks[tid] = kind; u.t.ws[tid] = w; u.t.bs[tid] = b;
      u.t.jr[tid] = -1;
    }
    __syncthreads();
    if (tid == 0){
      int c = 0;
      for (int q = 0; q < 128; q++) c += (u.t.ks[q] != 2) ? 1 : 0;
      nfp[0] = c;
    }
    if (tid < 128){
      int j = tid;
      float t = u.t.ts[j];
      int r = 0;
      for (int q = 0; q < 128; q++){
        if (u.t.ks[q] != 2){
          float tq = u.t.ts[q];
          if (tq < t || (tq == t && q < j)) r++;
        }
      }
      t1[j] = t;
      if (u.t.ks[j] != 2) u.t.jr[r] = j;
    }
    __syncthreads();
    if (tid < 128){
      int k = tid;
      float a = 0.f, c = 0.f;
      for (int q = 0; q < 128; q++){    // segment 0: kind1 all active
        int kd = u.t.ks[q];
        bool act = (kd == 1) || (kd == 2 && u.t.bs[q] > 0.0f);
        if (act){ float v = u.t.w2s[q*HD + k]; a = fmaf(u.t.ws[q], v, a); c = fmaf(u.t.bs[q], v, c); }
      }
      int base = (k>>2)*8 + (k&3);
      AC1[base] = a; AC1[base+4] = c;
      for (int s = 0; s < 128; s++){
        int q = u.t.jr[s];
        if (q >= 0){
          float sg = (u.t.ks[q] == 0) ? 1.f : -1.f;
          float v  = u.t.w2s[q*HD + k];
          a = fmaf(sg*u.t.ws[q], v, a);
          c = fmaf(sg*u.t.bs[q], v, c);
        }
        int o = (s+1)*256 + base;
        AC1[o] = a; AC1[o+4] = c;
      }
    }
    return;
  }

  // ---------------- CSR for graph g ----------------
  int g = blockIdx.x;
  for (int k = tid; k < NNPG; k += 1024) u.c.cnt[k] = 0;
  __syncthreads();
  const int* srcs = ei + g*EPG;
  const int* dsts = ei + ET + g*EPG;
  int gbase = g*NNPG;
  #pragma unroll
  for (int k = 0; k < EPG/1024; k++){
    int d = dsts[k*1024 + tid] - gbase;
    atomicAdd(&u.c.cnt[d], 1);
  }
  __syncthreads();
  int n0 = u.c.cnt[4*tid+0], n1 = u.c.cnt[4*tid+1];
  int n2 = u.c.cnt[4*tid+2], n3 = u.c.cnt[4*tid+3];
  int p0 = (n0+3)&~3, p1 = (n1+3)&~3, p2 = (n2+3)&~3, p3 = (n3+3)&~3;
  int tsum = p0+p1+p2+p3;
  u.c.tsum[tid] = tsum;
  __syncthreads();
  for (int d = 1; d < 1024; d <<= 1){
    int v = (tid >= d) ? u.c.tsum[tid-d] : 0;
    __syncthreads();
    u.c.tsum[tid] += v;
    __syncthreads();
  }
  int tbase = u.c.tsum[tid] - tsum;     // exclusive
  int sbase = g*SLOTPG;
  int o0 = tbase, o1 = o0+p0, o2 = o1+p1, o3 = o2+p2;
  int i0 = gbase + 4*tid;
  cnt[i0+0] = n0; cnt[i0+1] = n1; cnt[i0+2] = n2; cnt[i0+3] = n3;
  off[i0+0] = sbase+o0; off[i0+1] = sbase+o1; off[i0+2] = sbase+o2; off[i0+3] = sbase+o3;
  xd[i0+0] = make_float2(x[i0+0], rsqrtf((float)n0 + 1.0f));
  xd[i0+1] = make_float2(x[i0+1], rsqrtf((float)n1 + 1.0f));
  xd[i0+2] = make_float2(x[i0+2], rsqrtf((float)n2 + 1.0f));
  xd[i0+3] = make_float2(x[i0+3], rsqrtf((float)n3 + 1.0f));
  for (int s = n0; s < p0; s++) csrc[sbase+o0+s] = -1;
  for (int s = n1; s < p1; s++) csrc[sbase+o1+s] = -1;
  for (int s = n2; s < p2; s++) csrc[sbase+o2+s] = -1;
  for (int s = n3; s < p3; s++) csrc[sbase+o3+s] = -1;
  __syncthreads();
  u.c.cnt[4*tid+0] = o0; u.c.cnt[4*tid+1] = o1;
  u.c.cnt[4*tid+2] = o2; u.c.cnt[4*tid+3] = o3;
  __syncthreads();
  #pragma unroll
  for (int k = 0; k < EPG/1024; k++){
    int e = k*1024 + tid;
    int s = srcs[e], d = dsts[e] - gbase;
    int p = atomicAdd(&u.c.cnt[d], 1);
    csrc[sbase + p] = s;
  }
}

// ---- per-node records: recN[2i]=(d, d*ax, d*srow, segE) recN[2i+1]=(eo,np,0,0)
__global__ void k_ax(const float2* __restrict__ xd,
                     const int* __restrict__ off, const int* __restrict__ cnt,
                     const int* __restrict__ csrc, const float* __restrict__ t1,
                     float4* __restrict__ recN, float* __restrict__ srowA){
  __shared__ float ts[128];
  if (threadIdx.x < 128) ts[threadIdx.x] = t1[threadIdx.x];
  __syncthreads();
  int i = blockIdx.x*256 + threadIdx.x;
  float2 own = xd[i];
  float di = own.y;
  int eo = off[i], n = cnt[i];
  float sx = di * own.x, s1 = di;       // self-loop terms
  int t = 0;
  for (; t + 4 <= n; t += 4){
    int a = csrc[eo+t], b = csrc[eo+t+1], c = csrc[eo+t+2], d = csrc[eo+t+3];
    float2 xa = xd[a], xb = xd[b], xc = xd[c], xdd = xd[d];
    sx += xa.y*xa.x + xb.y*xb.x + xc.y*xc.x + xdd.y*xdd.x;
    s1 += xa.y + xb.y + xc.y + xdd.y;
  }
  for (; t < n; ++t){
    float2 xs = xd[csrc[eo + t]];
    sx += xs.y * xs.x; s1 += xs.y;
  }
  float a_ = di * sx, sr = di * s1;
  int sc = 0;
  for (int q = 0; q < 128; q++) sc += (ts[q] < a_) ? 1 : 0;
  int np = (n + 3) & ~3;
  recN[2*i]   = make_float4(di, di*a_, di*sr, __int_as_float(sc));
  recN[2*i+1] = make_float4(__int_as_float(eo), __int_as_float(np), 0.f, 0.f);
  srowA[i] = sr;
}

// per-edge scalar accumulation (enc: VAL = r.y = d*ax; dec: VAL = r.z = d*srow)
#define EDGE_ACC(r, VAL, SB) do{ \
  int sb_ = (SB); \
  float v_ = (VAL); \
  swa += v_; sw += r.x; \
  bool isN_ = (sb_ == nf) && (sb_ != 0); \
  swaN += isN_ ? v_  : 0.f; \
  swN  += isN_ ? r.x : 0.f; \
  if (sb_ != 0 && sb_ != nf){ \
    const float4* qm_ = AC + ((size_t)sb_*32 + lane)*2; \
    float4 qa_ = qm_[0], qc_ = qm_[1]; \
    mx = fmaf(v_, qa_.x-A0.x, fmaf(r.x, qc_.x-C0.x, mx)); \
    my = fmaf(v_, qa_.y-A0.y, fmaf(r.x, qc_.y-C0.y, my)); \
    mz = fmaf(v_, qa_.z-A0.z, fmaf(r.x, qc_.z-C0.z, mz)); \
    mw = fmaf(v_, qa_.w-A0.w, fmaf(r.x, qc_.w-C0.w, mw)); \
  } \
}while(0)

// ---------------- fused encoder GCN2 + relu + mean-pool ----------------
__global__ void __launch_bounds__(256) k_enc_agg(
    const float4* __restrict__ recN, const int* __restrict__ csrc,
    const float4* __restrict__ AC, const float* __restrict__ b2,
    const int* __restrict__ nfp, float* __restrict__ hgsum)
{
  __shared__ float4 sSlot[SCAP];
  __shared__ float4 sRec[TN*2];
  __shared__ float red[256*4];
  int bid = blockIdx.x, g = bid & 63, part = bid >> 6;
  int tid = threadIdx.x, lane = tid & 31, nrow = tid >> 5;
  int base = g*NNPG + part*TN;
  int nf = nfp[0];
  int so = __float_as_int(recN[2*base+1].x);
  float4 rL = recN[2*(base+TN-1)+1];
  int se = __float_as_int(rL.x) + __float_as_int(rL.y);
  int total = se - so;
  int nstage = total < SCAP ? total : SCAP;
  for (int idx = tid; idx < TN*2; idx += 256) sRec[idx] = recN[2*base + idx];
  for (int idx = tid; idx < nstage; idx += 256){
    int s = csrc[so + idx];
    sSlot[idx] = (s < 0) ? make_float4(0.f,0.f,0.f,0.f) : recN[2*s];
  }
  __syncthreads();
  const float4* q0 = AC + (size_t)lane*2;
  const float4* qn = AC + ((size_t)nf*32 + lane)*2;
  float4 A0 = q0[0], C0 = q0[1], An = qn[0], Cn = qn[1];
  float4 dA = make_float4(An.x-A0.x, An.y-A0.y, An.z-A0.z, An.w-A0.w);
  float4 dC = make_float4(Cn.x-C0.x, Cn.y-C0.y, Cn.z-C0.z, Cn.w-C0.w);
  float4 bb = ((const float4*)b2)[lane];
  float gx=0.f, gy=0.f, gz=0.f, gw=0.f;
  for (int it = 0; it < TN/8; ++it){
    int li = it*8 + nrow;
    float4 rA = sRec[2*li], rB = sRec[2*li+1];
    int eo = __float_as_int(rB.x), np = __float_as_int(rB.y);
    int lo = eo - so;
    int nin = nstage - lo; nin = nin < 0 ? 0 : (nin > np ? np : nin);
    float swa=0.f, sw=0.f, swaN=0.f, swN=0.f;
    float mx=0.f, my=0.f, mz=0.f, mw=0.f;
    for (int t = 0; t < nin; t += 4){
      float4 r1 = sSlot[lo+t], r2 = sSlot[lo+t+1], r3 = sSlot[lo+t+2], r4 = sSlot[lo+t+3];
      EDGE_ACC(r1, r1.y, __float_as_int(r1.w));
      EDGE_ACC(r2, r2.y, __float_as_int(r2.w));
      EDGE_ACC(r3, r3.y, __float_as_int(r3.w));
      EDGE_ACC(r4, r4.y, __float_as_int(r4.w));
    }
    for (int t = nin; t < np; t += 4){          // overflow fallback (rare)
      #pragma unroll
      for (int u = 0; u < 4; u++){
        int s = csrc[eo+t+u];
        float4 r = (s < 0) ? make_float4(0.f,0.f,0.f,0.f) : recN[2*s];
        EDGE_ACC(r, r.y, __float_as_int(r.w));
      }
    }
    float accx = fmaf(swa,A0.x, fmaf(swaN,dA.x, fmaf(sw,C0.x, fmaf(swN,dC.x, mx))));
    float accy = fmaf(swa,A0.y, fmaf(swaN,dA.y, fmaf(sw,C0.y, fmaf(swN,dC.y, my))));
    float accz = fmaf(swa,A0.z, fmaf(swaN,dA.z, fmaf(sw,C0.z, fmaf(swN,dC.z, mz))));
    float accw = fmaf(swa,A0.w, fmaf(swaN,dA.w, fmaf(sw,C0.w, fmaf(swN,dC.w, mw))));
    int si = __float_as_int(rA.w);
    bool m0 = (si == 0);
    float4 sa, sc;
    sa.x = m0 ? A0.x : An.x; sa.y = m0 ? A0.y : An.y; sa.z = m0 ? A0.z : An.z; sa.w = m0 ? A0.w : An.w;
    sc.x = m0 ? C0.x : Cn.x; sc.y = m0 ? C0.y : Cn.y; sc.z = m0 ? C0.z : Cn.z; sc.w = m0 ? C0.w : Cn.w;
    if (si != 0 && si != nf){
      const float4* qs = AC + ((size_t)si*32 + lane)*2;
      sa = qs[0]; sc = qs[1];
    }
    float d = rA.x, d2 = d*d, ca = rA.y*d;      // d^2 * ax
    gx += fmaxf(fmaf(d, accx, fmaf(ca, sa.x, d2*sc.x)) + bb.x, 0.f);
    gy += fmaxf(fmaf(d, accy, fmaf(ca, sa.y, d2*sc.y)) + bb.y, 0.f);
    gz += fmaxf(fmaf(d, accz, fmaf(ca, sa.z, d2*sc.z)) + bb.z, 0.f);
    gw += fmaxf(fmaf(d, accw, fmaf(ca, sa.w, d2*sc.w)) + bb.w, 0.f);
  }
  __syncthreads();
  red[tid*4+0] = gx; red[tid*4+1] = gy; red[tid*4+2] = gz; red[tid*4+3] = gw;
  __syncthreads();
  if (nrow == 0){
    float tx=0.f, ty=0.f, tz=0.f, tw=0.f;
    for (int r2 = 0; r2 < 8; r2++){
      int t2 = (r2*32 + lane)*4;
      tx += red[t2]; ty += red[t2+1]; tz += red[t2+2]; tw += red[t2+3];
    }
    atomicAdd(&hgsum[g*HD + lane*4 + 0], tx);
    atomicAdd(&hgsum[g*HD + lane*4 + 1], ty);
    atomicAdd(&hgsum[g*HD + lane*4 + 2], tz);
    atomicAdd(&hgsum[g*HD + lane*4 + 3], tw);
  }
}

// ------- per-graph dense chain (slim: no table build) -------
__global__ void __launch_bounds__(128) k_small(
    const float* __restrict__ hgsum,
    const float* __restrict__ mu_w, const float* __restrict__ mu_b,
    const float* __restrict__ lv_w, const float* __restrict__ lv_b,
    const float* __restrict__ eps,
    const float* __restrict__ zn_w, const float* __restrict__ zn_b,
    const float* __restrict__ dec_w1, const float* __restrict__ dec_b1,
    float* __restrict__ out_mu, float* __restrict__ out_lv, float* __restrict__ out_z,
    float* __restrict__ t2, float* __restrict__ ushG, int* __restrict__ nf2)
{
  int g = blockIdx.x, tid = threadIdx.x;
  __shared__ float hg[128], zsh[64], znsh[128];
  __shared__ int ks[128];
  hg[tid] = hgsum[g*HD + tid] * (1.0f/4096.0f);
  __syncthreads();
  if (tid < 64){
    int l = tid;
    float m = mu_b[l], v = lv_b[l];
    for (int k = 0; k < HD; k++){
      float hv = hg[k];
      m = fmaf(hv, mu_w[k*LD + l], m);
      v = fmaf(hv, lv_w[k*LD + l], v);
    }
    int o = g*LD + l;
    out_mu[o] = m; out_lv[o] = v;
    float zv = fmaf(expf(0.5f*v), eps[o], m);
    out_z[o] = zv; zsh[l] = zv;
  }
  __syncthreads();
  {
    int k = tid;
    float acc = zn_b[k];
    for (int l = 0; l < LD; l++) acc = fmaf(zsh[l], zn_w[l*HD + k], acc);
    znsh[k] = acc;
  }
  __syncthreads();
  float w;
  {
    int k = tid;
    float acc = 0.f;
    for (int j = 0; j < HD; j++) acc = fmaf(znsh[j], dec_w1[j*HD + k], acc);
    ushG[g*HD + k] = acc;
    w = acc;
  }
  float b = dec_b1[tid];
  float t; int kind;
  if (w != 0.0f){ t = -b / w; kind = (w > 0.0f) ? 0 : 1; }
  else          { t = INFINITY; kind = 2; }
  t2[g*HD + tid] = t; ks[tid] = kind;
  __syncthreads();
  if (tid == 0){
    int c = 0;
    for (int q = 0; q < 128; q++) c += (ks[q] != 2) ? 1 : 0;
    nf2[g] = c;
  }
}

// segD per node -> overwrite recN[2i].y (d*ax, dead after encoder) + used bitmap
__global__ void k_seg2(const float* __restrict__ t2, const float* __restrict__ srowA,
                       float* __restrict__ recNf, int* __restrict__ segUsed){
  __shared__ float ts[128];
  __shared__ int used[8];
  int tid = threadIdx.x;
  int i = blockIdx.x*256 + tid;
  int g = blockIdx.x >> 4;
  if (tid < 128) ts[tid] = t2[g*HD + tid];
  if (tid < 8) used[tid] = 0;
  __syncthreads();
  float a = srowA[i];
  int sc = 0;
  for (int q = 0; q < 128; q++) sc += (ts[q] < a) ? 1 : 0;
  recNf[(2*i)*4 + 1] = __int_as_float(sc);
  atomicOr(&used[sc>>5], 1u << (sc & 31));
  __syncthreads();
  if (tid < 8 && used[tid]) atomicOr(&segUsed[g*8 + tid], used[tid]);
}

// ---- build only the USED decoder table rows (plus rows 0 and nf) ----
// active(s): kind0: rank<s; kind1: rank>=s; kind2: b>0
__global__ void __launch_bounds__(128) k_tab2rows(
    const float* __restrict__ ushG, const float* __restrict__ dec_b1,
    const float* __restrict__ w2, const int* __restrict__ segUsed,
    const int* __restrict__ nf2, float* __restrict__ AC2)
{
  __shared__ float ws[128], bs[128], tsh[128];
  __shared__ int ks[128], rr[128];
  int g = blockIdx.x, j = threadIdx.x;
  float w = ushG[g*HD + j], b = dec_b1[j];
  float t; int kind;
  if (w != 0.0f){ t = -b / w; kind = (w > 0.0f) ? 0 : 1; }
  else          { t = INFINITY; kind = 2; }
  ws[j] = w; bs[j] = b; tsh[j] = t; ks[j] = kind;
  __syncthreads();
  int r = 0;
  for (int q = 0; q < 128; q++){
    if (ks[q] != 2){
      float tq = tsh[q];
      if (tq < t || (tq == t && q < j)) r++;
    }
  }
  rr[j] = r;
  __syncthreads();
  int nf = nf2[g];
  float* ACg = AC2 + (size_t)g*NSEG*256;
  int base = (j>>2)*8 + (j&3);
  for (int wd = 0; wd < 5; wd++){
    unsigned m = (unsigned)segUsed[g*8 + wd];
    if (wd == 0) m |= 1u;                        // row 0 always
    if ((nf >> 5) == wd) m |= 1u << (nf & 31);   // row nf always
    while (m){
      int bit = __ffs(m) - 1;
      m &= m - 1;
      int s = wd*32 + bit;
      float a = 0.f, c = 0.f;
      for (int q = 0; q < 128; q++){
        int kd = ks[q];
        bool act = (kd == 0) ? (rr[q] < s) : (kd == 1) ? (rr[q] >= s) : (bs[q] > 0.0f);
        if (act){ float v = w2[q*HD + j]; a = fmaf(ws[q], v, a); c = fmaf(bs[q], v, c); }
      }
      ACg[s*256 + base] = a; ACg[s*256 + base + 4] = c;
    }
  }
}

// ---------------- fused decoder GCN2 + relu + out-proj + tanh ----------------
// recN[2i] = (d, segD, d*srow, segE_unused)
__global__ void __launch_bounds__(256) k_dec_agg(
    const float4* __restrict__ recN, const int* __restrict__ csrc,
    const float4* __restrict__ AC2, const float* __restrict__ b2,
    const float* __restrict__ ow, const float* __restrict__ ob,
    const int* __restrict__ nf2, float* __restrict__ recon)
{
  __shared__ float4 sSlot[SCAP];
  __shared__ float4 sRec[TN*2];
  int bid = blockIdx.x, g = bid & 63, part = bid >> 6;
  int tid = threadIdx.x, lane = tid & 31, nrow = tid >> 5;
  int base = g*NNPG + part*TN;
  int nf = nf2[g];
  const float4* AC = AC2 + (size_t)g*NSEG*64;
  int so = __float_as_int(recN[2*base+1].x);
  float4 rL = recN[2*(base+TN-1)+1];
  int se = __float_as_int(rL.x) + __float_as_int(rL.y);
  int total = se - so;
  int nstage = total < SCAP ? total : SCAP;
  for (int idx = tid; idx < TN*2; idx += 256) sRec[idx] = recN[2*base + idx];
  for (int idx = tid; idx < nstage; idx += 256){
    int s = csrc[so + idx];
    sSlot[idx] = (s < 0) ? make_float4(0.f,0.f,0.f,0.f) : recN[2*s];
  }
  __syncthreads();
  const float4* q0 = AC + (size_t)lane*2;
  const float4* qn = AC + ((size_t)nf*32 + lane)*2;
  float4 A0 = q0[0], C0 = q0[1], An = qn[0], Cn = qn[1];
  float4 dA = make_float4(An.x-A0.x, An.y-A0.y, An.z-A0.z, An.w-A0.w);
  float4 dC = make_float4(Cn.x-C0.x, Cn.y-C0.y, Cn.z-C0.z, Cn.w-C0.w);
  float4 bb  = ((const float4*)b2)[lane];
  float4 owv = ((const float4*)ow)[lane];
  float obv = ob[0];
  for (int it = 0; it < TN/8; ++it){
    int li = it*8 + nrow;
    float4 rA = sRec[2*li], rB = sRec[2*li+1];
    int eo = __float_as_int(rB.x), np = __float_as_int(rB.y);
    int lo = eo - so;
    int nin = nstage - lo; nin = nin < 0 ? 0 : (nin > np ? np : nin);
    float swa=0.f, sw=0.f, swaN=0.f, swN=0.f;
    float mx=0.f, my=0.f, mz=0.f, mw=0.f;
    for (int t = 0; t < nin; t += 4){
      float4 r1 = sSlot[lo+t], r2 = sSlot[lo+t+1], r3 = sSlot[lo+t+2], r4 = sSlot[lo+t+3];
      EDGE_ACC(r1, r1.z, __float_as_int(r1.y));
      EDGE_ACC(r2, r2.z, __float_as_int(r2.y));
      EDGE_ACC(r3, r3.z, __float_as_int(r3.y));
      EDGE_ACC(r4, r4.z, __float_as_int(r4.y));
    }
    for (int t = nin; t < np; t += 4){          // overflow fallback (rare)
      #pragma unroll
      for (int u = 0; u < 4; u++){
        int s = csrc[eo+t+u];
        float4 r = (s < 0) ? make_float4(0.f,0.f,0.f,0.f) : recN[2*s];
        EDGE_ACC(r, r.z, __float_as_int(r.y));
      }
    }
    float accx = fmaf(swa,A0.x, fmaf(swaN,dA.x, fmaf(sw,C0.x, fmaf(swN,dC.x, mx))));
    float accy = fmaf(swa,A0.y, fmaf(swaN,dA.y, fmaf(sw,C0.y, fmaf(swN,dC.y, my))));
    float accz = fmaf(swa,A0.z, fmaf(swaN,dA.z, fmaf(sw,C0.z, fmaf(swN,dC.z, mz))));
    float accw = fmaf(swa,A0.w, fmaf(swaN,dA.w, fmaf(sw,C0.w, fmaf(swN,dC.w, mw))));
    int si = __float_as_int(rA.y);
    bool m0 = (si == 0);
    float4 sa, sc;
    sa.x = m0 ? A0.x : An.x; sa.y = m0 ? A0.y : An.y; sa.z = m0 ? A0.z : An.z; sa.w = m0 ? A0.w : An.w;
    sc.x = m0 ? C0.x : Cn.x; sc.y = m0 ? C0.y : Cn.y; sc.z = m0 ? C0.z : Cn.z; sc.w = m0 ? C0.w : Cn.w;
    if (si != 0 && si != nf){
      const float4* qs = AC + ((size_t)si*32 + lane)*2;
      sa = qs[0]; sc = qs[1];
    }
    float d = rA.x, d2 = d*d, ca = rA.z*d;      // d^2 * srow
    float hx = fmaxf(fmaf(d, accx, fmaf(ca, sa.x, d2*sc.x)) + bb.x, 0.f);
    float hy = fmaxf(fmaf(d, accy, fmaf(ca, sa.y, d2*sc.y)) + bb.y, 0.f);
    float hz = fmaxf(fmaf(d, accz, fmaf(ca, sa.z, d2*sc.z)) + bb.z, 0.f);
    float hw = fmaxf(fmaf(d, accw, fmaf(ca, sa.w, d2*sc.w)) + bb.w, 0.f);
    float dsum = hx*owv.x + hy*owv.y + hz*owv.z + hw*owv.w;
    for (int o2 = 16; o2 > 0; o2 >>= 1) dsum += __shfl_down(dsum, o2, 32);
    if (lane == 0) recon[base + li] = tanhf(dsum + obv);
  }
}

// ---------------- launch ----------------
extern "C" void kernel_launch(void* const* d_in, const int* in_sizes, int n_in,
                              void* d_out, int out_size, void* d_ws, size_t ws_size,
                              hipStream_t stream){
  (void)in_sizes; (void)n_in; (void)out_size; (void)ws_size;
  const float* x      = (const float*)d_in[0];
  const float* eps    = (const float*)d_in[1];
  const float* enc_w1 = (const float*)d_in[2];
  const float* enc_b1 = (const float*)d_in[3];
  const float* enc_w2 = (const float*)d_in[4];
  const float* enc_b2 = (const float*)d_in[5];
  const float* mu_w   = (const float*)d_in[6];
  const float* mu_b   = (const float*)d_in[7];
  const float* lv_w   = (const float*)d_in[8];
  const float* lv_b   = (const float*)d_in[9];
  const float* zn_w   = (const float*)d_in[10];
  const float* zn_b   = (const float*)d_in[11];
  const float* dec_w1 = (const float*)d_in[12];
  const float* dec_b1 = (const float*)d_in[13];
  const float* dec_w2 = (const float*)d_in[14];
  const float* dec_b2 = (const float*)d_in[15];
  const float* out_w  = (const float*)d_in[16];
  const float* out_b  = (const float*)d_in[17];
  const int*   ei     = (const int*)d_in[18];

  float* out       = (float*)d_out;
  float* out_recon = out;
  float* out_mu    = out + NTOT;
  float* out_lv    = out_mu + BG*LD;
  float* out_z     = out_lv + BG*LD;

  char* w = (char*)d_ws;
  size_t off_b = 0;
  auto alloc = [&](size_t bytes)->void*{
    void* p = w + off_b;
    off_b += (bytes + 255) & ~(size_t)255;
    return p;
  };
  int*    cnt    = (int*)   alloc((size_t)NTOT*4);
  int*    eoP    = (int*)   alloc((size_t)NTOT*4);
  int*    csrc   = (int*)   alloc((size_t)SLOTCAP*4);
  float2* xd     = (float2*)alloc((size_t)NTOT*8);
  float4* recN   = (float4*)alloc(((size_t)NTOT*2 + 32)*16);
  float*  srowA  = (float*) alloc((size_t)NTOT*4);
  float*  t1     = (float*) alloc(128*4);
  int*    nf1    = (int*)   alloc(256);
  int*    nf2    = (int*)   alloc(BG*4);
  int*    segU   = (int*)   alloc(BG*8*4);
  float*  ushG   = (float*) alloc((size_t)BG*HD*4);
  float*  AC1    = (float*) alloc((size_t)NSEG*256*4);
  float*  hgsum  = (float*) alloc((size_t)BG*HD*4);
  float*  t2     = (float*) alloc((size_t)BG*HD*4);
  float*  AC2    = (float*) alloc((size_t)BG*NSEG*256*4);

  hipMemsetAsync(hgsum, 0, (size_t)BG*HD*4, stream);
  hipMemsetAsync(segU,  0, (size_t)BG*8*4, stream);

  k_csr<<<BG+1, 1024, 0, stream>>>(ei, x, enc_w1, enc_b1, enc_w2,
                                   cnt, eoP, csrc, xd, t1, AC1, nf1);

  k_ax<<<NTOT/256, 256, 0, stream>>>(xd, eoP, cnt, csrc, t1, recN, srowA);

  k_enc_agg<<<2048, 256, 0, stream>>>(recN, csrc, (const float4*)AC1, enc_b2, nf1, hgsum);

  k_small<<<BG, 128, 0, stream>>>(hgsum, mu_w, mu_b, lv_w, lv_b, eps,
                                  zn_w, zn_b, dec_w1, dec_b1,
                                  out_mu, out_lv, out_z, t2, ushG, nf2);

  k_seg2<<<NTOT/256, 256, 0, stream>>>(t2, srowA, (float*)recN, segU);

  k_tab2rows<<<BG, 128, 0, stream>>>(ushG, dec_b1, dec_w2, segU, nf2, AC2);

  k_dec_agg<<<2048, 256, 0, stream>>>(recN, csrc, (const float4*)AC2,
                                      dec_b2, out_w, out_b, nf2, out_recon);
}

// Round 7
// 211.619 us; speedup vs baseline: 1.0506x; 1.0506x over previous
//
#include <hip/hip_runtime.h>
#include <math.h>

#define NTOT 262144   // total nodes
#define BG   64       // graphs
#define NNPG 4096     // nodes per graph
#define ET   1048576  // directed edges
#define EPG  16384    // edges per graph
#define HD   128
#define LD   64
#define NSEG 129
#define SLOTPG 28672  // max padded slots per graph (EPG + 3*NNPG)
#define SLOTCAP (BG*SLOTPG)
#define TN   128      // nodes per agg tile
#define SCAP 1152     // staged slots per tile (fallback to global past this)

// ======== fused CSR build (1 block/graph, LDS atomics) + tab1 (block 64) ====
// tab1: relu(a*w1[j]+b1[j]): kind 0: w>0, kind 1: w<0, kind 2: w==0 (act iff b>0).
// Incremental: segment s->s+1 flips exactly the unit with rank s.
// AC float layout: s*256 + (k>>2)*8 + (k&3), +4 for C  (per (s,lane) 32B pair)
__global__ void __launch_bounds__(1024) k_csr(
    const int* __restrict__ ei, const float* __restrict__ x,
    const float* __restrict__ w1, const float* __restrict__ b1,
    const float* __restrict__ w2,
    int* __restrict__ cnt, int* __restrict__ off, int* __restrict__ csrc,
    float2* __restrict__ xd,
    float* __restrict__ t1, float* __restrict__ AC1, int* __restrict__ nfp)
{
  __shared__ union {
    struct { int cnt[NNPG]; int tsum[1024]; } c;
    struct { float w2s[HD*HD]; float ts[128], ws[128], bs[128]; int ks[128], jr[128]; } t;
  } u;
  int tid = threadIdx.x;

  if (blockIdx.x == BG){
    // ---------------- tab1 ----------------
    {
      const float4* src = (const float4*)w2;
      float4* dst = (float4*)u.t.w2s;
      for (int idx = tid; idx < HD*HD/4; idx += 1024) dst[idx] = src[idx];
    }
    if (tid < 128){
      float w = w1[tid], b = b1[tid];
      float t; int kind;
      if (w != 0.0f){ t = -b / w; kind = (w > 0.0f) ? 0 : 1; }
      else          { t = INFINITY; kind = 2; }
      u.t.ts[tid] = t; u.t.ks[tid] = kind; u.t.ws[tid] = w; u.t.bs[tid] = b;
      u.t.jr[tid] = -1;
    }
    __syncthreads();
    if (tid == 0){
      int c = 0;
      for (int q = 0; q < 128; q++) c += (u.t.ks[q] != 2) ? 1 : 0;
      nfp[0] = c;
    }
    if (tid < 128){
      int j = tid;
      float t = u.t.ts[j];
      int r = 0;
      for (int q = 0; q < 128; q++){
        if (u.t.ks[q] != 2){
          float tq = u.t.ts[q];
          if (tq < t || (tq == t && q < j)) r++;
        }
      }
      t1[j] = t;
      if (u.t.ks[j] != 2) u.t.jr[r] = j;
    }
    __syncthreads();
    if (tid < 128){
      int k = tid;
      float a = 0.f, c = 0.f;
      for (int q = 0; q < 128; q++){    // segment 0: kind1 all active
        int kd = u.t.ks[q];
        bool act = (kd == 1) || (kd == 2 && u.t.bs[q] > 0.0f);
        if (act){ float v = u.t.w2s[q*HD + k]; a = fmaf(u.t.ws[q], v, a); c = fmaf(u.t.bs[q], v, c); }
      }
      int base = (k>>2)*8 + (k&3);
      AC1[base] = a; AC1[base+4] = c;
      for (int s = 0; s < 128; s++){
        int q = u.t.jr[s];
        if (q >= 0){
          float sg = (u.t.ks[q] == 0) ? 1.f : -1.f;
          float v  = u.t.w2s[q*HD + k];
          a = fmaf(sg*u.t.ws[q], v, a);
          c = fmaf(sg*u.t.bs[q], v, c);
        }
        int o = (s+1)*256 + base;
        AC1[o] = a; AC1[o+4] = c;
      }
    }
    return;
  }

  // ---------------- CSR for graph g ----------------
  int g = blockIdx.x;
  for (int k = tid; k < NNPG; k += 1024) u.c.cnt[k] = 0;
  __syncthreads();
  const int* srcs = ei + g*EPG;
  const int* dsts = ei + ET + g*EPG;
  int gbase = g*NNPG;
  #pragma unroll
  for (int k = 0; k < EPG/1024; k++){
    int d = dsts[k*1024 + tid] - gbase;
    atomicAdd(&u.c.cnt[d], 1);
  }
  __syncthreads();
  int n0 = u.c.cnt[4*tid+0], n1 = u.c.cnt[4*tid+1];
  int n2 = u.c.cnt[4*tid+2], n3 = u.c.cnt[4*tid+3];
  int p0 = (n0+3)&~3, p1 = (n1+3)&~3, p2 = (n2+3)&~3, p3 = (n3+3)&~3;
  int tsum = p0+p1+p2+p3;
  u.c.tsum[tid] = tsum;
  __syncthreads();
  for (int d = 1; d < 1024; d <<= 1){
    int v = (tid >= d) ? u.c.tsum[tid-d] : 0;
    __syncthreads();
    u.c.tsum[tid] += v;
    __syncthreads();
  }
  int tbase = u.c.tsum[tid] - tsum;     // exclusive
  int sbase = g*SLOTPG;
  int o0 = tbase, o1 = o0+p0, o2 = o1+p1, o3 = o2+p2;
  int i0 = gbase + 4*tid;
  cnt[i0+0] = n0; cnt[i0+1] = n1; cnt[i0+2] = n2; cnt[i0+3] = n3;
  off[i0+0] = sbase+o0; off[i0+1] = sbase+o1; off[i0+2] = sbase+o2; off[i0+3] = sbase+o3;
  xd[i0+0] = make_float2(x[i0+0], rsqrtf((float)n0 + 1.0f));
  xd[i0+1] = make_float2(x[i0+1], rsqrtf((float)n1 + 1.0f));
  xd[i0+2] = make_float2(x[i0+2], rsqrtf((float)n2 + 1.0f));
  xd[i0+3] = make_float2(x[i0+3], rsqrtf((float)n3 + 1.0f));
  for (int s = n0; s < p0; s++) csrc[sbase+o0+s] = -1;
  for (int s = n1; s < p1; s++) csrc[sbase+o1+s] = -1;
  for (int s = n2; s < p2; s++) csrc[sbase+o2+s] = -1;
  for (int s = n3; s < p3; s++) csrc[sbase+o3+s] = -1;
  __syncthreads();
  u.c.cnt[4*tid+0] = o0; u.c.cnt[4*tid+1] = o1;
  u.c.cnt[4*tid+2] = o2; u.c.cnt[4*tid+3] = o3;
  __syncthreads();
  #pragma unroll
  for (int k = 0; k < EPG/1024; k++){
    int e = k*1024 + tid;
    int s = srcs[e], d = dsts[e] - gbase;
    int p = atomicAdd(&u.c.cnt[d], 1);
    csrc[sbase + p] = s;
  }
}

// ---- per-node records: recN[2i]=(d, d*ax, d*srow, segE) recN[2i+1]=(eo,np,0,0)
__global__ void k_ax(const float2* __restrict__ xd,
                     const int* __restrict__ off, const int* __restrict__ cnt,
                     const int* __restrict__ csrc, const float* __restrict__ t1,
                     float4* __restrict__ recN, float* __restrict__ srowA){
  __shared__ float ts[128];
  if (threadIdx.x < 128) ts[threadIdx.x] = t1[threadIdx.x];
  __syncthreads();
  int i = blockIdx.x*256 + threadIdx.x;
  float2 own = xd[i];
  float di = own.y;
  int eo = off[i], n = cnt[i];
  float sx = di * own.x, s1 = di;       // self-loop terms
  int t = 0;
  for (; t + 4 <= n; t += 4){
    int a = csrc[eo+t], b = csrc[eo+t+1], c = csrc[eo+t+2], d = csrc[eo+t+3];
    float2 xa = xd[a], xb = xd[b], xc = xd[c], xdd = xd[d];
    sx += xa.y*xa.x + xb.y*xb.x + xc.y*xc.x + xdd.y*xdd.x;
    s1 += xa.y + xb.y + xc.y + xdd.y;
  }
  for (; t < n; ++t){
    float2 xs = xd[csrc[eo + t]];
    sx += xs.y * xs.x; s1 += xs.y;
  }
  float a_ = di * sx, sr = di * s1;
  int sc = 0;
  for (int q = 0; q < 128; q++) sc += (ts[q] < a_) ? 1 : 0;
  int np = (n + 3) & ~3;
  recN[2*i]   = make_float4(di, di*a_, di*sr, __int_as_float(sc));
  recN[2*i+1] = make_float4(__int_as_float(eo), __int_as_float(np), 0.f, 0.f);
  srowA[i] = sr;
}

// per-edge scalar accumulation (enc: VAL = r.y = d*ax; dec: VAL = r.z = d*srow)
#define EDGE_ACC(r, VAL, SB) do{ \
  int sb_ = (SB); \
  float v_ = (VAL); \
  swa += v_; sw += r.x; \
  bool isN_ = (sb_ == nf) && (sb_ != 0); \
  swaN += isN_ ? v_  : 0.f; \
  swN  += isN_ ? r.x : 0.f; \
  if (sb_ != 0 && sb_ != nf){ \
    const float4* qm_ = AC + ((size_t)sb_*32 + lane)*2; \
    float4 qa_ = qm_[0], qc_ = qm_[1]; \
    mx = fmaf(v_, qa_.x-A0.x, fmaf(r.x, qc_.x-C0.x, mx)); \
    my = fmaf(v_, qa_.y-A0.y, fmaf(r.x, qc_.y-C0.y, my)); \
    mz = fmaf(v_, qa_.z-A0.z, fmaf(r.x, qc_.z-C0.z, mz)); \
    mw = fmaf(v_, qa_.w-A0.w, fmaf(r.x, qc_.w-C0.w, mw)); \
  } \
}while(0)

// ---------------- fused encoder GCN2 + relu + mean-pool ----------------
__global__ void __launch_bounds__(256) k_enc_agg(
    const float4* __restrict__ recN, const int* __restrict__ csrc,
    const float4* __restrict__ AC, const float* __restrict__ b2,
    const int* __restrict__ nfp, float* __restrict__ hgsum)
{
  __shared__ float4 sSlot[SCAP];
  __shared__ float4 sRec[TN*2];
  __shared__ float red[256*4];
  int bid = blockIdx.x, g = bid & 63, part = bid >> 6;
  int tid = threadIdx.x, lane = tid & 31, nrow = tid >> 5;
  int base = g*NNPG + part*TN;
  int nf = nfp[0];
  int so = __float_as_int(recN[2*base+1].x);
  float4 rL = recN[2*(base+TN-1)+1];
  int se = __float_as_int(rL.x) + __float_as_int(rL.y);
  int total = se - so;
  int nstage = total < SCAP ? total : SCAP;
  for (int idx = tid; idx < TN*2; idx += 256) sRec[idx] = recN[2*base + idx];
  for (int idx = tid; idx < nstage; idx += 256){
    int s = csrc[so + idx];
    sSlot[idx] = (s < 0) ? make_float4(0.f,0.f,0.f,0.f) : recN[2*s];
  }
  __syncthreads();
  const float4* q0 = AC + (size_t)lane*2;
  const float4* qn = AC + ((size_t)nf*32 + lane)*2;
  float4 A0 = q0[0], C0 = q0[1], An = qn[0], Cn = qn[1];
  float4 dA = make_float4(An.x-A0.x, An.y-A0.y, An.z-A0.z, An.w-A0.w);
  float4 dC = make_float4(Cn.x-C0.x, Cn.y-C0.y, Cn.z-C0.z, Cn.w-C0.w);
  float4 bb = ((const float4*)b2)[lane];
  float gx=0.f, gy=0.f, gz=0.f, gw=0.f;
  for (int it = 0; it < TN/8; ++it){
    int li = it*8 + nrow;
    float4 rA = sRec[2*li], rB = sRec[2*li+1];
    int eo = __float_as_int(rB.x), np = __float_as_int(rB.y);
    int lo = eo - so;
    int nin = nstage - lo; nin = nin < 0 ? 0 : (nin > np ? np : nin);
    float swa=0.f, sw=0.f, swaN=0.f, swN=0.f;
    float mx=0.f, my=0.f, mz=0.f, mw=0.f;
    for (int t = 0; t < nin; t += 4){
      float4 r1 = sSlot[lo+t], r2 = sSlot[lo+t+1], r3 = sSlot[lo+t+2], r4 = sSlot[lo+t+3];
      EDGE_ACC(r1, r1.y, __float_as_int(r1.w));
      EDGE_ACC(r2, r2.y, __float_as_int(r2.w));
      EDGE_ACC(r3, r3.y, __float_as_int(r3.w));
      EDGE_ACC(r4, r4.y, __float_as_int(r4.w));
    }
    for (int t = nin; t < np; t += 4){          // overflow fallback (rare)
      #pragma unroll
      for (int u = 0; u < 4; u++){
        int s = csrc[eo+t+u];
        float4 r = (s < 0) ? make_float4(0.f,0.f,0.f,0.f) : recN[2*s];
        EDGE_ACC(r, r.y, __float_as_int(r.w));
      }
    }
    float accx = fmaf(swa,A0.x, fmaf(swaN,dA.x, fmaf(sw,C0.x, fmaf(swN,dC.x, mx))));
    float accy = fmaf(swa,A0.y, fmaf(swaN,dA.y, fmaf(sw,C0.y, fmaf(swN,dC.y, my))));
    float accz = fmaf(swa,A0.z, fmaf(swaN,dA.z, fmaf(sw,C0.z, fmaf(swN,dC.z, mz))));
    float accw = fmaf(swa,A0.w, fmaf(swaN,dA.w, fmaf(sw,C0.w, fmaf(swN,dC.w, mw))));
    int si = __float_as_int(rA.w);
    bool m0 = (si == 0);
    float4 sa, sc;
    sa.x = m0 ? A0.x : An.x; sa.y = m0 ? A0.y : An.y; sa.z = m0 ? A0.z : An.z; sa.w = m0 ? A0.w : An.w;
    sc.x = m0 ? C0.x : Cn.x; sc.y = m0 ? C0.y : Cn.y; sc.z = m0 ? C0.z : Cn.z; sc.w = m0 ? C0.w : Cn.w;
    if (si != 0 && si != nf){
      const float4* qs = AC + ((size_t)si*32 + lane)*2;
      sa = qs[0]; sc = qs[1];
    }
    float d = rA.x, d2 = d*d, ca = rA.y*d;      // d^2 * ax
    gx += fmaxf(fmaf(d, accx, fmaf(ca, sa.x, d2*sc.x)) + bb.x, 0.f);
    gy += fmaxf(fmaf(d, accy, fmaf(ca, sa.y, d2*sc.y)) + bb.y, 0.f);
    gz += fmaxf(fmaf(d, accz, fmaf(ca, sa.z, d2*sc.z)) + bb.z, 0.f);
    gw += fmaxf(fmaf(d, accw, fmaf(ca, sa.w, d2*sc.w)) + bb.w, 0.f);
  }
  __syncthreads();
  red[tid*4+0] = gx; red[tid*4+1] = gy; red[tid*4+2] = gz; red[tid*4+3] = gw;
  __syncthreads();
  if (nrow == 0){
    float tx=0.f, ty=0.f, tz=0.f, tw=0.f;
    for (int r2 = 0; r2 < 8; r2++){
      int t2 = (r2*32 + lane)*4;
      tx += red[t2]; ty += red[t2+1]; tz += red[t2+2]; tw += red[t2+3];
    }
    atomicAdd(&hgsum[g*HD + lane*4 + 0], tx);
    atomicAdd(&hgsum[g*HD + lane*4 + 1], ty);
    atomicAdd(&hgsum[g*HD + lane*4 + 2], tz);
    atomicAdd(&hgsum[g*HD + lane*4 + 3], tw);
  }
}

// ------- per-graph dense chain (slim: no table build) -------
__global__ void __launch_bounds__(128) k_small(
    const float* __restrict__ hgsum,
    const float* __restrict__ mu_w, const float* __restrict__ mu_b,
    const float* __restrict__ lv_w, const float* __restrict__ lv_b,
    const float* __restrict__ eps,
    const float* __restrict__ zn_w, const float* __restrict__ zn_b,
    const float* __restrict__ dec_w1, const float* __restrict__ dec_b1,
    float* __restrict__ out_mu, float* __restrict__ out_lv, float* __restrict__ out_z,
    float* __restrict__ t2, float* __restrict__ ushG, int* __restrict__ nf2)
{
  int g = blockIdx.x, tid = threadIdx.x;
  __shared__ float hg[128], zsh[64], znsh[128];
  __shared__ int ks[128];
  hg[tid] = hgsum[g*HD + tid] * (1.0f/4096.0f);
  __syncthreads();
  if (tid < 64){
    int l = tid;
    float m = mu_b[l], v = lv_b[l];
    for (int k = 0; k < HD; k++){
      float hv = hg[k];
      m = fmaf(hv, mu_w[k*LD + l], m);
      v = fmaf(hv, lv_w[k*LD + l], v);
    }
    int o = g*LD + l;
    out_mu[o] = m; out_lv[o] = v;
    float zv = fmaf(expf(0.5f*v), eps[o], m);
    out_z[o] = zv; zsh[l] = zv;
  }
  __syncthreads();
  {
    int k = tid;
    float acc = zn_b[k];
    for (int l = 0; l < LD; l++) acc = fmaf(zsh[l], zn_w[l*HD + k], acc);
    znsh[k] = acc;
  }
  __syncthreads();
  float w;
  {
    int k = tid;
    float acc = 0.f;
    for (int j = 0; j < HD; j++) acc = fmaf(znsh[j], dec_w1[j*HD + k], acc);
    ushG[g*HD + k] = acc;
    w = acc;
  }
  float b = dec_b1[tid];
  float t; int kind;
  if (w != 0.0f){ t = -b / w; kind = (w > 0.0f) ? 0 : 1; }
  else          { t = INFINITY; kind = 2; }
  t2[g*HD + tid] = t; ks[tid] = kind;
  __syncthreads();
  if (tid == 0){
    int c = 0;
    for (int q = 0; q < 128; q++) c += (ks[q] != 2) ? 1 : 0;
    nf2[g] = c;
  }
}

// segD per node -> overwrite recN[2i].y (d*ax, dead after encoder) + used bitmap
__global__ void k_seg2(const float* __restrict__ t2, const float* __restrict__ srowA,
                       float* __restrict__ recNf, int* __restrict__ segUsed){
  __shared__ float ts[128];
  __shared__ int used[8];
  int tid = threadIdx.x;
  int i = blockIdx.x*256 + tid;
  int g = blockIdx.x >> 4;
  if (tid < 128) ts[tid] = t2[g*HD + tid];
  if (tid < 8) used[tid] = 0;
  __syncthreads();
  float a = srowA[i];
  int sc = 0;
  for (int q = 0; q < 128; q++) sc += (ts[q] < a) ? 1 : 0;
  recNf[(2*i)*4 + 1] = __int_as_float(sc);
  atomicOr(&used[sc>>5], 1u << (sc & 31));
  __syncthreads();
  if (tid < 8 && used[tid]) atomicOr(&segUsed[g*8 + tid], used[tid]);
}

// ---- build only the USED decoder table rows (plus rows 0 and nf) ----
// active(s): kind0: rank<s; kind1: rank>=s; kind2: b>0
// dec_w2 staged in LDS (coalesced float4) so the q-loop has pipelined ds_reads
__global__ void __launch_bounds__(128) k_tab2rows(
    const float* __restrict__ ushG, const float* __restrict__ dec_b1,
    const float* __restrict__ w2, const int* __restrict__ segUsed,
    const int* __restrict__ nf2, float* __restrict__ AC2)
{
  __shared__ float w2s[HD*HD];
  __shared__ float ws[128], bs[128], tsh[128];
  __shared__ int ks[128], rr[128];
  int g = blockIdx.x, j = threadIdx.x;
  {
    const float4* src = (const float4*)w2;
    float4* dst = (float4*)w2s;
    #pragma unroll
    for (int idx = 0; idx < HD*HD/4/128; idx++) dst[idx*128 + j] = src[idx*128 + j];
  }
  float w = ushG[g*HD + j], b = dec_b1[j];
  float t; int kind;
  if (w != 0.0f){ t = -b / w; kind = (w > 0.0f) ? 0 : 1; }
  else          { t = INFINITY; kind = 2; }
  ws[j] = w; bs[j] = b; tsh[j] = t; ks[j] = kind;
  __syncthreads();
  int r = 0;
  for (int q = 0; q < 128; q++){
    if (ks[q] != 2){
      float tq = tsh[q];
      if (tq < t || (tq == t && q < j)) r++;
    }
  }
  rr[j] = r;
  __syncthreads();
  int nf = nf2[g];
  float* ACg = AC2 + (size_t)g*NSEG*256;
  int base = (j>>2)*8 + (j&3);
  for (int wd = 0; wd < 5; wd++){
    unsigned m = (unsigned)segUsed[g*8 + wd];
    if (wd == 0) m |= 1u;                        // row 0 always
    if ((nf >> 5) == wd) m |= 1u << (nf & 31);   // row nf always
    while (m){
      int bit = __ffs(m) - 1;
      m &= m - 1;
      int s = wd*32 + bit;
      float a = 0.f, c = 0.f;
      #pragma unroll 8
      for (int q = 0; q < 128; q++){
        int kd = ks[q];
        bool act = (kd == 0) ? (rr[q] < s) : (kd == 1) ? (rr[q] >= s) : (bs[q] > 0.0f);
        float v = act ? w2s[q*HD + j] : 0.0f;
        a = fmaf(ws[q], v, a); c = fmaf(bs[q], v, c);
      }
      ACg[s*256 + base] = a; ACg[s*256 + base + 4] = c;
    }
  }
}

// ---------------- fused decoder GCN2 + relu + out-proj + tanh ----------------
// recN[2i] = (d, segD, d*srow, segE_unused)
__global__ void __launch_bounds__(256) k_dec_agg(
    const float4* __restrict__ recN, const int* __restrict__ csrc,
    const float4* __restrict__ AC2, const float* __restrict__ b2,
    const float* __restrict__ ow, const float* __restrict__ ob,
    const int* __restrict__ nf2, float* __restrict__ recon)
{
  __shared__ float4 sSlot[SCAP];
  __shared__ float4 sRec[TN*2];
  int bid = blockIdx.x, g = bid & 63, part = bid >> 6;
  int tid = threadIdx.x, lane = tid & 31, nrow = tid >> 5;
  int base = g*NNPG + part*TN;
  int nf = nf2[g];
  const float4* AC = AC2 + (size_t)g*NSEG*64;
  int so = __float_as_int(recN[2*base+1].x);
  float4 rL = recN[2*(base+TN-1)+1];
  int se = __float_as_int(rL.x) + __float_as_int(rL.y);
  int total = se - so;
  int nstage = total < SCAP ? total : SCAP;
  for (int idx = tid; idx < TN*2; idx += 256) sRec[idx] = recN[2*base + idx];
  for (int idx = tid; idx < nstage; idx += 256){
    int s = csrc[so + idx];
    sSlot[idx] = (s < 0) ? make_float4(0.f,0.f,0.f,0.f) : recN[2*s];
  }
  __syncthreads();
  const float4* q0 = AC + (size_t)lane*2;
  const float4* qn = AC + ((size_t)nf*32 + lane)*2;
  float4 A0 = q0[0], C0 = q0[1], An = qn[0], Cn = qn[1];
  float4 dA = make_float4(An.x-A0.x, An.y-A0.y, An.z-A0.z, An.w-A0.w);
  float4 dC = make_float4(Cn.x-C0.x, Cn.y-C0.y, Cn.z-C0.z, Cn.w-C0.w);
  float4 bb  = ((const float4*)b2)[lane];
  float4 owv = ((const float4*)ow)[lane];
  float obv = ob[0];
  for (int it = 0; it < TN/8; ++it){
    int li = it*8 + nrow;
    float4 rA = sRec[2*li], rB = sRec[2*li+1];
    int eo = __float_as_int(rB.x), np = __float_as_int(rB.y);
    int lo = eo - so;
    int nin = nstage - lo; nin = nin < 0 ? 0 : (nin > np ? np : nin);
    float swa=0.f, sw=0.f, swaN=0.f, swN=0.f;
    float mx=0.f, my=0.f, mz=0.f, mw=0.f;
    for (int t = 0; t < nin; t += 4){
      float4 r1 = sSlot[lo+t], r2 = sSlot[lo+t+1], r3 = sSlot[lo+t+2], r4 = sSlot[lo+t+3];
      EDGE_ACC(r1, r1.z, __float_as_int(r1.y));
      EDGE_ACC(r2, r2.z, __float_as_int(r2.y));
      EDGE_ACC(r3, r3.z, __float_as_int(r3.y));
      EDGE_ACC(r4, r4.z, __float_as_int(r4.y));
    }
    for (int t = nin; t < np; t += 4){          // overflow fallback (rare)
      #pragma unroll
      for (int u = 0; u < 4; u++){
        int s = csrc[eo+t+u];
        float4 r = (s < 0) ? make_float4(0.f,0.f,0.f,0.f) : recN[2*s];
        EDGE_ACC(r, r.z, __float_as_int(r.y));
      }
    }
    float accx = fmaf(swa,A0.x, fmaf(swaN,dA.x, fmaf(sw,C0.x, fmaf(swN,dC.x, mx))));
    float accy = fmaf(swa,A0.y, fmaf(swaN,dA.y, fmaf(sw,C0.y, fmaf(swN,dC.y, my))));
    float accz = fmaf(swa,A0.z, fmaf(swaN,dA.z, fmaf(sw,C0.z, fmaf(swN,dC.z, mz))));
    float accw = fmaf(swa,A0.w, fmaf(swaN,dA.w, fmaf(sw,C0.w, fmaf(swN,dC.w, mw))));
    int si = __float_as_int(rA.y);
    bool m0 = (si == 0);
    float4 sa, sc;
    sa.x = m0 ? A0.x : An.x; sa.y = m0 ? A0.y : An.y; sa.z = m0 ? A0.z : An.z; sa.w = m0 ? A0.w : An.w;
    sc.x = m0 ? C0.x : Cn.x; sc.y = m0 ? C0.y : Cn.y; sc.z = m0 ? C0.z : Cn.z; sc.w = m0 ? C0.w : Cn.w;
    if (si != 0 && si != nf){
      const float4* qs = AC + ((size_t)si*32 + lane)*2;
      sa = qs[0]; sc = qs[1];
    }
    float d = rA.x, d2 = d*d, ca = rA.z*d;      // d^2 * srow
    float hx = fmaxf(fmaf(d, accx, fmaf(ca, sa.x, d2*sc.x)) + bb.x, 0.f);
    float hy = fmaxf(fmaf(d, accy, fmaf(ca, sa.y, d2*sc.y)) + bb.y, 0.f);
    float hz = fmaxf(fmaf(d, accz, fmaf(ca, sa.z, d2*sc.z)) + bb.z, 0.f);
    float hw = fmaxf(fmaf(d, accw, fmaf(ca, sa.w, d2*sc.w)) + bb.w, 0.f);
    float dsum = hx*owv.x + hy*owv.y + hz*owv.z + hw*owv.w;
    for (int o2 = 16; o2 > 0; o2 >>= 1) dsum += __shfl_down(dsum, o2, 32);
    if (lane == 0) recon[base + li] = tanhf(dsum + obv);
  }
}

// ---------------- launch ----------------
extern "C" void kernel_launch(void* const* d_in, const int* in_sizes, int n_in,
                              void* d_out, int out_size, void* d_ws, size_t ws_size,
                              hipStream_t stream){
  (void)in_sizes; (void)n_in; (void)out_size; (void)ws_size;
  const float* x      = (const float*)d_in[0];
  const float* eps    = (const float*)d_in[1];
  const float* enc_w1 = (const float*)d_in[2];
  const float* enc_b1 = (const float*)d_in[3];
  const float* enc_w2 = (const float*)d_in[4];
  const float* enc_b2 = (const float*)d_in[5];
  const float* mu_w   = (const float*)d_in[6];
  const float* mu_b   = (const float*)d_in[7];
  const float* lv_w   = (const float*)d_in[8];
  const float* lv_b   = (const float*)d_in[9];
  const float* zn_w   = (const float*)d_in[10];
  const float* zn_b   = (const float*)d_in[11];
  const float* dec_w1 = (const float*)d_in[12];
  const float* dec_b1 = (const float*)d_in[13];
  const float* dec_w2 = (const float*)d_in[14];
  const float* dec_b2 = (const float*)d_in[15];
  const float* out_w  = (const float*)d_in[16];
  const float* out_b  = (const float*)d_in[17];
  const int*   ei     = (const int*)d_in[18];

  float* out       = (float*)d_out;
  float* out_recon = out;
  float* out_mu    = out + NTOT;
  float* out_lv    = out_mu + BG*LD;
  float* out_z     = out_lv + BG*LD;

  char* w = (char*)d_ws;
  size_t off_b = 0;
  auto alloc = [&](size_t bytes)->void*{
    void* p = w + off_b;
    off_b += (bytes + 255) & ~(size_t)255;
    return p;
  };
  int*    cnt    = (int*)   alloc((size_t)NTOT*4);
  int*    eoP    = (int*)   alloc((size_t)NTOT*4);
  int*    csrc   = (int*)   alloc((size_t)SLOTCAP*4);
  float2* xd     = (float2*)alloc((size_t)NTOT*8);
  float4* recN   = (float4*)alloc(((size_t)NTOT*2 + 32)*16);
  float*  srowA  = (float*) alloc((size_t)NTOT*4);
  float*  t1     = (float*) alloc(128*4);
  int*    nf1    = (int*)   alloc(256);
  int*    nf2    = (int*)   alloc(BG*4);
  int*    segU   = (int*)   alloc(BG*8*4);
  float*  ushG   = (float*) alloc((size_t)BG*HD*4);
  float*  AC1    = (float*) alloc((size_t)NSEG*256*4);
  float*  hgsum  = (float*) alloc((size_t)BG*HD*4);
  float*  t2     = (float*) alloc((size_t)BG*HD*4);
  float*  AC2    = (float*) alloc((size_t)BG*NSEG*256*4);

  hipMemsetAsync(hgsum, 0, (size_t)BG*HD*4, stream);
  hipMemsetAsync(segU,  0, (size_t)BG*8*4, stream);

  k_csr<<<BG+1, 1024, 0, stream>>>(ei, x, enc_w1, enc_b1, enc_w2,
                                   cnt, eoP, csrc, xd, t1, AC1, nf1);

  k_ax<<<NTOT/256, 256, 0, stream>>>(xd, eoP, cnt, csrc, t1, recN, srowA);

  k_enc_agg<<<2048, 256, 0, stream>>>(recN, csrc, (const float4*)AC1, enc_b2, nf1, hgsum);

  k_small<<<BG, 128, 0, stream>>>(hgsum, mu_w, mu_b, lv_w, lv_b, eps,
                                  zn_w, zn_b, dec_w1, dec_b1,
                                  out_mu, out_lv, out_z, t2, ushG, nf2);

  k_seg2<<<NTOT/256, 256, 0, stream>>>(t2, srowA, (float*)recN, segU);

  k_tab2rows<<<BG, 128, 0, stream>>>(ushG, dec_b1, dec_w2, segU, nf2, AC2);

  k_dec_agg<<<2048, 256, 0, stream>>>(recN, csrc, (const float4*)AC2,
                                      dec_b2, out_w, out_b, nf2, out_recon);
}

// Round 8
// 184.958 us; speedup vs baseline: 1.2021x; 1.1441x over previous
//
#include <hip/hip_runtime.h>
#include <math.h>

#define NTOT 262144   // total nodes
#define BG   64       // graphs
#define NNPG 4096     // nodes per graph
#define ET   1048576  // directed edges
#define EPG  16384    // edges per graph
#define HD   128
#define LD   64
#define NSEG 129
#define SLOTPG 28672  // max padded slots per graph (EPG + 3*NNPG)
#define SLOTCAP (BG*SLOTPG)
#define TN   256      // nodes per agg tile (one per thread in phase 1)

// ======== fused CSR build + ax/srow accumulation (1 block/graph, LDS) ======
// block BG runs tab1: relu(a*w1[j]+b1[j]) piecewise-linear table, incremental.
// AC float layout: s*256 + (k>>2)*8 + (k&3), +4 for C  (per (s,lane) 32B pair)
__global__ void __launch_bounds__(1024) k_csr(
    const int* __restrict__ ei, const float* __restrict__ x,
    const float* __restrict__ w1, const float* __restrict__ b1,
    const float* __restrict__ w2,
    int* __restrict__ cnt, int* __restrict__ off, int* __restrict__ csrc,
    float2* __restrict__ axsr,
    float* __restrict__ t1, float* __restrict__ AC1, int* __restrict__ nfp)
{
  __shared__ union {
    struct { int cur[NNPG]; float xs[NNPG]; float dinvs[NNPG];
             float axs[NNPG]; float s1s[NNPG]; int tsum[1024]; } c;
    struct { float w2s[HD*HD]; float ts[128], ws[128], bs[128];
             int ks[128], jr[128]; } t;
  } u;
  int tid = threadIdx.x;

  if (blockIdx.x == BG){
    // ---------------- tab1 ----------------
    {
      const float4* src = (const float4*)w2;
      float4* dst = (float4*)u.t.w2s;
      for (int idx = tid; idx < HD*HD/4; idx += 1024) dst[idx] = src[idx];
    }
    if (tid < 128){
      float w = w1[tid], b = b1[tid];
      float t; int kind;
      if (w != 0.0f){ t = -b / w; kind = (w > 0.0f) ? 0 : 1; }
      else          { t = INFINITY; kind = 2; }
      u.t.ts[tid] = t; u.t.ks[tid] = kind; u.t.ws[tid] = w; u.t.bs[tid] = b;
      u.t.jr[tid] = -1;
    }
    __syncthreads();
    if (tid == 0){
      int c = 0;
      for (int q = 0; q < 128; q++) c += (u.t.ks[q] != 2) ? 1 : 0;
      nfp[0] = c;
    }
    if (tid < 128){
      int j = tid;
      float t = u.t.ts[j];
      int r = 0;
      for (int q = 0; q < 128; q++){
        if (u.t.ks[q] != 2){
          float tq = u.t.ts[q];
          if (tq < t || (tq == t && q < j)) r++;
        }
      }
      t1[j] = t;
      if (u.t.ks[j] != 2) u.t.jr[r] = j;
    }
    __syncthreads();
    if (tid < 128){
      int k = tid;
      float a = 0.f, c = 0.f;
      for (int q = 0; q < 128; q++){    // segment 0: kind1 all active
        int kd = u.t.ks[q];
        bool act = (kd == 1) || (kd == 2 && u.t.bs[q] > 0.0f);
        if (act){ float v = u.t.w2s[q*HD + k]; a = fmaf(u.t.ws[q], v, a); c = fmaf(u.t.bs[q], v, c); }
      }
      int base = (k>>2)*8 + (k&3);
      AC1[base] = a; AC1[base+4] = c;
      for (int s = 0; s < 128; s++){
        int q = u.t.jr[s];
        if (q >= 0){
          float sg = (u.t.ks[q] == 0) ? 1.f : -1.f;
          float v  = u.t.w2s[q*HD + k];
          a = fmaf(sg*u.t.ws[q], v, a);
          c = fmaf(sg*u.t.bs[q], v, c);
        }
        int o = (s+1)*256 + base;
        AC1[o] = a; AC1[o+4] = c;
      }
    }
    return;
  }

  // ---------------- CSR + ax/srow for graph g ----------------
  int g = blockIdx.x;
  int gbase = g*NNPG;
  for (int k = tid; k < NNPG; k += 1024){
    u.c.cur[k] = 0; u.c.axs[k] = 0.f; u.c.s1s[k] = 0.f;
    u.c.xs[k] = x[gbase + k];
  }
  __syncthreads();
  const int* srcs = ei + g*EPG;
  const int* dsts = ei + ET + g*EPG;
  #pragma unroll
  for (int k = 0; k < EPG/1024; k++){
    int d = dsts[k*1024 + tid] - gbase;
    atomicAdd(&u.c.cur[d], 1);
  }
  __syncthreads();
  int n0 = u.c.cur[4*tid+0], n1 = u.c.cur[4*tid+1];
  int n2 = u.c.cur[4*tid+2], n3 = u.c.cur[4*tid+3];
  u.c.dinvs[4*tid+0] = rsqrtf((float)n0 + 1.0f);
  u.c.dinvs[4*tid+1] = rsqrtf((float)n1 + 1.0f);
  u.c.dinvs[4*tid+2] = rsqrtf((float)n2 + 1.0f);
  u.c.dinvs[4*tid+3] = rsqrtf((float)n3 + 1.0f);
  int p0 = (n0+3)&~3, p1 = (n1+3)&~3, p2 = (n2+3)&~3, p3 = (n3+3)&~3;
  int tsum = p0+p1+p2+p3;
  u.c.tsum[tid] = tsum;
  __syncthreads();
  for (int d = 1; d < 1024; d <<= 1){
    int v = (tid >= d) ? u.c.tsum[tid-d] : 0;
    __syncthreads();
    u.c.tsum[tid] += v;
    __syncthreads();
  }
  int tbase = u.c.tsum[tid] - tsum;     // exclusive
  int sbase = g*SLOTPG;
  int o0 = tbase, o1 = o0+p0, o2 = o1+p1, o3 = o2+p2;
  int i0 = gbase + 4*tid;
  cnt[i0+0] = n0; cnt[i0+1] = n1; cnt[i0+2] = n2; cnt[i0+3] = n3;
  off[i0+0] = sbase+o0; off[i0+1] = sbase+o1; off[i0+2] = sbase+o2; off[i0+3] = sbase+o3;
  for (int s = n0; s < p0; s++) csrc[sbase+o0+s] = -1;
  for (int s = n1; s < p1; s++) csrc[sbase+o1+s] = -1;
  for (int s = n2; s < p2; s++) csrc[sbase+o2+s] = -1;
  for (int s = n3; s < p3; s++) csrc[sbase+o3+s] = -1;
  u.c.cur[4*tid+0] = o0; u.c.cur[4*tid+1] = o1;
  u.c.cur[4*tid+2] = o2; u.c.cur[4*tid+3] = o3;
  __syncthreads();
  #pragma unroll
  for (int k = 0; k < EPG/1024; k++){
    int e = k*1024 + tid;
    int s = srcs[e], d = dsts[e] - gbase;
    int sl = s - gbase;
    float v = u.c.dinvs[sl];
    int p = atomicAdd(&u.c.cur[d], 1);
    csrc[sbase + p] = s;
    atomicAdd(&u.c.axs[d], v * u.c.xs[sl]);
    atomicAdd(&u.c.s1s[d], v);
  }
  __syncthreads();
  #pragma unroll
  for (int j = 0; j < 4; j++){
    int k = 4*tid + j;
    float di = u.c.dinvs[k];
    float ax = di * (di * u.c.xs[k] + u.c.axs[k]);
    float sr = di * (di + u.c.s1s[k]);
    axsr[gbase + k] = make_float2(ax, sr);
  }
}

// ---- pack per-node records (gather-free): recN[2i]=(d, d*ax, d*srow, segE),
// recN[2i+1]=(eo,np,0,0); srowA for decoder segs
__global__ void k_pack(const float2* __restrict__ axsr,
                       const int* __restrict__ off, const int* __restrict__ cnt,
                       const float* __restrict__ t1,
                       float4* __restrict__ recN, float* __restrict__ srowA){
  __shared__ float ts[128];
  if (threadIdx.x < 128) ts[threadIdx.x] = t1[threadIdx.x];
  __syncthreads();
  int i = blockIdx.x*256 + threadIdx.x;
  int n = cnt[i], eo = off[i];
  float di = rsqrtf((float)n + 1.0f);
  float2 as = axsr[i];
  int sc = 0;
  for (int q = 0; q < 128; q++) sc += (ts[q] < as.x) ? 1 : 0;
  int np = (n + 3) & ~3;
  recN[2*i]   = make_float4(di, di*as.x, di*as.y, __int_as_float(sc));
  recN[2*i+1] = make_float4(__int_as_float(eo), __int_as_float(np), 0.f, 0.f);
  srowA[i] = as.y;
}

// ---------------- fused encoder GCN2 + relu + mean-pool ----------------
// phase 1: one node per THREAD accumulates 4 edge-scalars (no 32x redundancy)
// phase 2: 32-lane dense tail per node; rare off-{0,nf} segs -> slow path
__global__ void __launch_bounds__(256) k_enc_agg(
    const float4* __restrict__ recN, const int* __restrict__ csrc,
    const float4* __restrict__ AC, const float* __restrict__ b2,
    const int* __restrict__ nfp, float* __restrict__ hgsum)
{
  __shared__ float4 sS[TN];
  __shared__ float4 sRA[TN];
  __shared__ int sFlag[TN];
  __shared__ float red[256*4];
  int bid = blockIdx.x, g = bid & 63, part = bid >> 6;   // 1024 blocks
  int tid = threadIdx.x, lane = tid & 31, nrow = tid >> 5;
  int base = g*NNPG + part*TN;
  int nf = nfp[0];
  {
    int i = base + tid;
    sRA[tid] = recN[2*i];
    float4 rB = recN[2*i+1];
    int eo = __float_as_int(rB.x), np = __float_as_int(rB.y);
    float swa=0.f, sw=0.f, swaN=0.f, swN=0.f;
    int flag = 0;
    for (int t = 0; t < np; t += 4){
      int4 ss = *(const int4*)(csrc + eo + t);
      #pragma unroll
      for (int uu = 0; uu < 4; uu++){
        int s = (uu==0)?ss.x:(uu==1)?ss.y:(uu==2)?ss.z:ss.w;
        if (s >= 0){
          float4 r = recN[2*s];
          int sb = __float_as_int(r.w);
          swa += r.y; sw += r.x;
          bool isN = (sb == nf) && (sb != 0);
          swaN += isN ? r.y : 0.f;
          swN  += isN ? r.x : 0.f;
          flag |= (sb != 0 && sb != nf) ? 1 : 0;
        }
      }
    }
    sS[tid] = make_float4(swa, sw, swaN, swN);
    sFlag[tid] = flag;
  }
  __syncthreads();
  const float4* q0 = AC + (size_t)lane*2;
  const float4* qn = AC + ((size_t)nf*32 + lane)*2;
  float4 A0 = q0[0], C0 = q0[1], An = qn[0], Cn = qn[1];
  float4 dA = make_float4(An.x-A0.x, An.y-A0.y, An.z-A0.z, An.w-A0.w);
  float4 dC = make_float4(Cn.x-C0.x, Cn.y-C0.y, Cn.z-C0.z, Cn.w-C0.w);
  float4 bb = ((const float4*)b2)[lane];
  float gx=0.f, gy=0.f, gz=0.f, gw=0.f;
  for (int it = 0; it < TN/8; ++it){
    int li = it*8 + nrow;
    int i = base + li;
    float4 rA = sRA[li];
    float accx, accy, accz, accw;
    if (sFlag[li]){              // rare slow path: full 32-wide recompute
      float4 rB = recN[2*i+1];
      int eo = __float_as_int(rB.x), np = __float_as_int(rB.y);
      float swa=0.f, sw=0.f, swaN=0.f, swN=0.f;
      float mx=0.f, my=0.f, mz=0.f, mw=0.f;
      for (int t = 0; t < np; ++t){
        int s = csrc[eo+t];
        if (s < 0) continue;
        float4 r = recN[2*s];
        int sb = __float_as_int(r.w);
        float v = r.y;
        swa += v; sw += r.x;
        bool isN = (sb == nf) && (sb != 0);
        swaN += isN ? v : 0.f; swN += isN ? r.x : 0.f;
        if (sb != 0 && sb != nf){
          const float4* qm = AC + ((size_t)sb*32 + lane)*2;
          float4 qa = qm[0], qc = qm[1];
          mx = fmaf(v, qa.x-A0.x, fmaf(r.x, qc.x-C0.x, mx));
          my = fmaf(v, qa.y-A0.y, fmaf(r.x, qc.y-C0.y, my));
          mz = fmaf(v, qa.z-A0.z, fmaf(r.x, qc.z-C0.z, mz));
          mw = fmaf(v, qa.w-A0.w, fmaf(r.x, qc.w-C0.w, mw));
        }
      }
      accx = fmaf(swa,A0.x, fmaf(swaN,dA.x, fmaf(sw,C0.x, fmaf(swN,dC.x, mx))));
      accy = fmaf(swa,A0.y, fmaf(swaN,dA.y, fmaf(sw,C0.y, fmaf(swN,dC.y, my))));
      accz = fmaf(swa,A0.z, fmaf(swaN,dA.z, fmaf(sw,C0.z, fmaf(swN,dC.z, mz))));
      accw = fmaf(swa,A0.w, fmaf(swaN,dA.w, fmaf(sw,C0.w, fmaf(swN,dC.w, mw))));
    } else {
      float4 s4 = sS[li];
      accx = fmaf(s4.x,A0.x, fmaf(s4.z,dA.x, fmaf(s4.y,C0.x, s4.w*dC.x)));
      accy = fmaf(s4.x,A0.y, fmaf(s4.z,dA.y, fmaf(s4.y,C0.y, s4.w*dC.y)));
      accz = fmaf(s4.x,A0.z, fmaf(s4.z,dA.z, fmaf(s4.y,C0.z, s4.w*dC.z)));
      accw = fmaf(s4.x,A0.w, fmaf(s4.z,dA.w, fmaf(s4.y,C0.w, s4.w*dC.w)));
    }
    int si = __float_as_int(rA.w);
    bool m0 = (si == 0);
    float4 sa, sc;
    sa.x = m0 ? A0.x : An.x; sa.y = m0 ? A0.y : An.y; sa.z = m0 ? A0.z : An.z; sa.w = m0 ? A0.w : An.w;
    sc.x = m0 ? C0.x : Cn.x; sc.y = m0 ? C0.y : Cn.y; sc.z = m0 ? C0.z : Cn.z; sc.w = m0 ? C0.w : Cn.w;
    if (si != 0 && si != nf){
      const float4* qs = AC + ((size_t)si*32 + lane)*2;
      sa = qs[0]; sc = qs[1];
    }
    float d = rA.x, d2 = d*d, ca = rA.y*d;
    gx += fmaxf(fmaf(d, accx, fmaf(ca, sa.x, d2*sc.x)) + bb.x, 0.f);
    gy += fmaxf(fmaf(d, accy, fmaf(ca, sa.y, d2*sc.y)) + bb.y, 0.f);
    gz += fmaxf(fmaf(d, accz, fmaf(ca, sa.z, d2*sc.z)) + bb.z, 0.f);
    gw += fmaxf(fmaf(d, accw, fmaf(ca, sa.w, d2*sc.w)) + bb.w, 0.f);
  }
  __syncthreads();
  red[tid*4+0] = gx; red[tid*4+1] = gy; red[tid*4+2] = gz; red[tid*4+3] = gw;
  __syncthreads();
  if (nrow == 0){
    float tx=0.f, ty=0.f, tz=0.f, tw=0.f;
    for (int r2 = 0; r2 < 8; r2++){
      int t2 = (r2*32 + lane)*4;
      tx += red[t2]; ty += red[t2+1]; tz += red[t2+2]; tw += red[t2+3];
    }
    atomicAdd(&hgsum[g*HD + lane*4 + 0], tx);
    atomicAdd(&hgsum[g*HD + lane*4 + 1], ty);
    atomicAdd(&hgsum[g*HD + lane*4 + 2], tz);
    atomicAdd(&hgsum[g*HD + lane*4 + 3], tw);
  }
}

// ------- per-graph dense chain (slim: no table build) -------
__global__ void __launch_bounds__(128) k_small(
    const float* __restrict__ hgsum,
    const float* __restrict__ mu_w, const float* __restrict__ mu_b,
    const float* __restrict__ lv_w, const float* __restrict__ lv_b,
    const float* __restrict__ eps,
    const float* __restrict__ zn_w, const float* __restrict__ zn_b,
    const float* __restrict__ dec_w1, const float* __restrict__ dec_b1,
    float* __restrict__ out_mu, float* __restrict__ out_lv, float* __restrict__ out_z,
    float* __restrict__ t2, float* __restrict__ ushG, int* __restrict__ nf2)
{
  int g = blockIdx.x, tid = threadIdx.x;
  __shared__ float hg[128], zsh[64], znsh[128];
  __shared__ int ks[128];
  hg[tid] = hgsum[g*HD + tid] * (1.0f/4096.0f);
  __syncthreads();
  if (tid < 64){
    int l = tid;
    float m = mu_b[l], v = lv_b[l];
    for (int k = 0; k < HD; k++){
      float hv = hg[k];
      m = fmaf(hv, mu_w[k*LD + l], m);
      v = fmaf(hv, lv_w[k*LD + l], v);
    }
    int o = g*LD + l;
    out_mu[o] = m; out_lv[o] = v;
    float zv = fmaf(expf(0.5f*v), eps[o], m);
    out_z[o] = zv; zsh[l] = zv;
  }
  __syncthreads();
  {
    int k = tid;
    float acc = zn_b[k];
    for (int l = 0; l < LD; l++) acc = fmaf(zsh[l], zn_w[l*HD + k], acc);
    znsh[k] = acc;
  }
  __syncthreads();
  float w;
  {
    int k = tid;
    float acc = 0.f;
    for (int j = 0; j < HD; j++) acc = fmaf(znsh[j], dec_w1[j*HD + k], acc);
    ushG[g*HD + k] = acc;
    w = acc;
  }
  float b = dec_b1[tid];
  float t; int kind;
  if (w != 0.0f){ t = -b / w; kind = (w > 0.0f) ? 0 : 1; }
  else          { t = INFINITY; kind = 2; }
  t2[g*HD + tid] = t; ks[tid] = kind;
  __syncthreads();
  if (tid == 0){
    int c = 0;
    for (int q = 0; q < 128; q++) c += (ks[q] != 2) ? 1 : 0;
    nf2[g] = c;
  }
}

// segD per node -> overwrite recN[2i].y (d*ax, dead after encoder) + used bitmap
__global__ void k_seg2(const float* __restrict__ t2, const float* __restrict__ srowA,
                       float* __restrict__ recNf, int* __restrict__ segUsed){
  __shared__ float ts[128];
  __shared__ int used[8];
  int tid = threadIdx.x;
  int i = blockIdx.x*256 + tid;
  int g = blockIdx.x >> 4;
  if (tid < 128) ts[tid] = t2[g*HD + tid];
  if (tid < 8) used[tid] = 0;
  __syncthreads();
  float a = srowA[i];
  int sc = 0;
  for (int q = 0; q < 128; q++) sc += (ts[q] < a) ? 1 : 0;
  recNf[(2*i)*4 + 1] = __int_as_float(sc);
  atomicOr(&used[sc>>5], 1u << (sc & 31));
  __syncthreads();
  if (tid < 8 && used[tid]) atomicOr(&segUsed[g*8 + tid], used[tid]);
}

// ---- build only the USED decoder table rows (plus rows 0 and nf) ----
__global__ void __launch_bounds__(128) k_tab2rows(
    const float* __restrict__ ushG, const float* __restrict__ dec_b1,
    const float* __restrict__ w2, const int* __restrict__ segUsed,
    const int* __restrict__ nf2, float* __restrict__ AC2)
{
  __shared__ float w2s[HD*HD];
  __shared__ float ws[128], bs[128], tsh[128];
  __shared__ int ks[128], rr[128];
  int g = blockIdx.x, j = threadIdx.x;
  {
    const float4* src = (const float4*)w2;
    float4* dst = (float4*)w2s;
    #pragma unroll
    for (int idx = 0; idx < HD*HD/4/128; idx++) dst[idx*128 + j] = src[idx*128 + j];
  }
  float w = ushG[g*HD + j], b = dec_b1[j];
  float t; int kind;
  if (w != 0.0f){ t = -b / w; kind = (w > 0.0f) ? 0 : 1; }
  else          { t = INFINITY; kind = 2; }
  ws[j] = w; bs[j] = b; tsh[j] = t; ks[j] = kind;
  __syncthreads();
  int r = 0;
  for (int q = 0; q < 128; q++){
    if (ks[q] != 2){
      float tq = tsh[q];
      if (tq < t || (tq == t && q < j)) r++;
    }
  }
  rr[j] = r;
  __syncthreads();
  int nf = nf2[g];
  float* ACg = AC2 + (size_t)g*NSEG*256;
  int base = (j>>2)*8 + (j&3);
  for (int wd = 0; wd < 5; wd++){
    unsigned m = (unsigned)segUsed[g*8 + wd];
    if (wd == 0) m |= 1u;
    if ((nf >> 5) == wd) m |= 1u << (nf & 31);
    while (m){
      int bit = __ffs(m) - 1;
      m &= m - 1;
      int s = wd*32 + bit;
      float a = 0.f, c = 0.f;
      #pragma unroll 8
      for (int q = 0; q < 128; q++){
        int kd = ks[q];
        bool act = (kd == 0) ? (rr[q] < s) : (kd == 1) ? (rr[q] >= s) : (bs[q] > 0.0f);
        float v = act ? w2s[q*HD + j] : 0.0f;
        a = fmaf(ws[q], v, a); c = fmaf(bs[q], v, c);
      }
      ACg[s*256 + base] = a; ACg[s*256 + base + 4] = c;
    }
  }
}

// ---------------- fused decoder GCN2 + relu + out-proj + tanh ----------------
// recN[2i] = (d, segD, d*srow, segE_unused)
__global__ void __launch_bounds__(256) k_dec_agg(
    const float4* __restrict__ recN, const int* __restrict__ csrc,
    const float4* __restrict__ AC2, const float* __restrict__ b2,
    const float* __restrict__ ow, const float* __restrict__ ob,
    const int* __restrict__ nf2, float* __restrict__ recon)
{
  __shared__ float4 sS[TN];
  __shared__ float4 sRA[TN];
  __shared__ int sFlag[TN];
  int bid = blockIdx.x, g = bid & 63, part = bid >> 6;
  int tid = threadIdx.x, lane = tid & 31, nrow = tid >> 5;
  int base = g*NNPG + part*TN;
  int nf = nf2[g];
  const float4* AC = AC2 + (size_t)g*NSEG*64;
  {
    int i = base + tid;
    sRA[tid] = recN[2*i];
    float4 rB = recN[2*i+1];
    int eo = __float_as_int(rB.x), np = __float_as_int(rB.y);
    float swa=0.f, sw=0.f, swaN=0.f, swN=0.f;
    int flag = 0;
    for (int t = 0; t < np; t += 4){
      int4 ss = *(const int4*)(csrc + eo + t);
      #pragma unroll
      for (int uu = 0; uu < 4; uu++){
        int s = (uu==0)?ss.x:(uu==1)?ss.y:(uu==2)?ss.z:ss.w;
        if (s >= 0){
          float4 r = recN[2*s];
          int sb = __float_as_int(r.y);
          swa += r.z; sw += r.x;
          bool isN = (sb == nf) && (sb != 0);
          swaN += isN ? r.z : 0.f;
          swN  += isN ? r.x : 0.f;
          flag |= (sb != 0 && sb != nf) ? 1 : 0;
        }
      }
    }
    sS[tid] = make_float4(swa, sw, swaN, swN);
    sFlag[tid] = flag;
  }
  __syncthreads();
  const float4* q0 = AC + (size_t)lane*2;
  const float4* qn = AC + ((size_t)nf*32 + lane)*2;
  float4 A0 = q0[0], C0 = q0[1], An = qn[0], Cn = qn[1];
  float4 dA = make_float4(An.x-A0.x, An.y-A0.y, An.z-A0.z, An.w-A0.w);
  float4 dC = make_float4(Cn.x-C0.x, Cn.y-C0.y, Cn.z-C0.z, Cn.w-C0.w);
  float4 bb  = ((const float4*)b2)[lane];
  float4 owv = ((const float4*)ow)[lane];
  float obv = ob[0];
  for (int it = 0; it < TN/8; ++it){
    int li = it*8 + nrow;
    int i = base + li;
    float4 rA = sRA[li];
    float accx, accy, accz, accw;
    if (sFlag[li]){              // rare slow path
      float4 rB = recN[2*i+1];
      int eo = __float_as_int(rB.x), np = __float_as_int(rB.y);
      float swa=0.f, sw=0.f, swaN=0.f, swN=0.f;
      float mx=0.f, my=0.f, mz=0.f, mw=0.f;
      for (int t = 0; t < np; ++t){
        int s = csrc[eo+t];
        if (s < 0) continue;
        float4 r = recN[2*s];
        int sb = __float_as_int(r.y);
        float v = r.z;
        swa += v; sw += r.x;
        bool isN = (sb == nf) && (sb != 0);
        swaN += isN ? v : 0.f; swN += isN ? r.x : 0.f;
        if (sb != 0 && sb != nf){
          const float4* qm = AC + ((size_t)sb*32 + lane)*2;
          float4 qa = qm[0], qc = qm[1];
          mx = fmaf(v, qa.x-A0.x, fmaf(r.x, qc.x-C0.x, mx));
          my = fmaf(v, qa.y-A0.y, fmaf(r.x, qc.y-C0.y, my));
          mz = fmaf(v, qa.z-A0.z, fmaf(r.x, qc.z-C0.z, mz));
          mw = fmaf(v, qa.w-A0.w, fmaf(r.x, qc.w-C0.w, mw));
        }
      }
      accx = fmaf(swa,A0.x, fmaf(swaN,dA.x, fmaf(sw,C0.x, fmaf(swN,dC.x, mx))));
      accy = fmaf(swa,A0.y, fmaf(swaN,dA.y, fmaf(sw,C0.y, fmaf(swN,dC.y, my))));
      accz = fmaf(swa,A0.z, fmaf(swaN,dA.z, fmaf(sw,C0.z, fmaf(swN,dC.z, mz))));
      accw = fmaf(swa,A0.w, fmaf(swaN,dA.w, fmaf(sw,C0.w, fmaf(swN,dC.w, mw))));
    } else {
      float4 s4 = sS[li];
      accx = fmaf(s4.x,A0.x, fmaf(s4.z,dA.x, fmaf(s4.y,C0.x, s4.w*dC.x)));
      accy = fmaf(s4.x,A0.y, fmaf(s4.z,dA.y, fmaf(s4.y,C0.y, s4.w*dC.y)));
      accz = fmaf(s4.x,A0.z, fmaf(s4.z,dA.z, fmaf(s4.y,C0.z, s4.w*dC.z)));
      accw = fmaf(s4.x,A0.w, fmaf(s4.z,dA.w, fmaf(s4.y,C0.w, s4.w*dC.w)));
    }
    int si = __float_as_int(rA.y);
    bool m0 = (si == 0);
    float4 sa, sc;
    sa.x = m0 ? A0.x : An.x; sa.y = m0 ? A0.y : An.y; sa.z = m0 ? A0.z : An.z; sa.w = m0 ? A0.w : An.w;
    sc.x = m0 ? C0.x : Cn.x; sc.y = m0 ? C0.y : Cn.y; sc.z = m0 ? C0.z : Cn.z; sc.w = m0 ? C0.w : Cn.w;
    if (si != 0 && si != nf){
      const float4* qs = AC + ((size_t)si*32 + lane)*2;
      sa = qs[0]; sc = qs[1];
    }
    float d = rA.x, d2 = d*d, ca = rA.z*d;
    float hx = fmaxf(fmaf(d, accx, fmaf(ca, sa.x, d2*sc.x)) + bb.x, 0.f);
    float hy = fmaxf(fmaf(d, accy, fmaf(ca, sa.y, d2*sc.y)) + bb.y, 0.f);
    float hz = fmaxf(fmaf(d, accz, fmaf(ca, sa.z, d2*sc.z)) + bb.z, 0.f);
    float hw = fmaxf(fmaf(d, accw, fmaf(ca, sa.w, d2*sc.w)) + bb.w, 0.f);
    float dsum = hx*owv.x + hy*owv.y + hz*owv.z + hw*owv.w;
    for (int o2 = 16; o2 > 0; o2 >>= 1) dsum += __shfl_down(dsum, o2, 32);
    if (lane == 0) recon[i] = tanhf(dsum + obv);
  }
}

// ---------------- launch ----------------
extern "C" void kernel_launch(void* const* d_in, const int* in_sizes, int n_in,
                              void* d_out, int out_size, void* d_ws, size_t ws_size,
                              hipStream_t stream){
  (void)in_sizes; (void)n_in; (void)out_size; (void)ws_size;
  const float* x      = (const float*)d_in[0];
  const float* eps    = (const float*)d_in[1];
  const float* enc_w1 = (const float*)d_in[2];
  const float* enc_b1 = (const float*)d_in[3];
  const float* enc_w2 = (const float*)d_in[4];
  const float* enc_b2 = (const float*)d_in[5];
  const float* mu_w   = (const float*)d_in[6];
  const float* mu_b   = (const float*)d_in[7];
  const float* lv_w   = (const float*)d_in[8];
  const float* lv_b   = (const float*)d_in[9];
  const float* zn_w   = (const float*)d_in[10];
  const float* zn_b   = (const float*)d_in[11];
  const float* dec_w1 = (const float*)d_in[12];
  const float* dec_b1 = (const float*)d_in[13];
  const float* dec_w2 = (const float*)d_in[14];
  const float* dec_b2 = (const float*)d_in[15];
  const float* out_w  = (const float*)d_in[16];
  const float* out_b  = (const float*)d_in[17];
  const int*   ei     = (const int*)d_in[18];

  float* out       = (float*)d_out;
  float* out_recon = out;
  float* out_mu    = out + NTOT;
  float* out_lv    = out_mu + BG*LD;
  float* out_z     = out_lv + BG*LD;

  char* w = (char*)d_ws;
  size_t off_b = 0;
  auto alloc = [&](size_t bytes)->void*{
    void* p = w + off_b;
    off_b += (bytes + 255) & ~(size_t)255;
    return p;
  };
  int*    cnt    = (int*)   alloc((size_t)NTOT*4);
  int*    eoP    = (int*)   alloc((size_t)NTOT*4);
  int*    csrc   = (int*)   alloc((size_t)SLOTCAP*4);
  float2* axsr   = (float2*)alloc((size_t)NTOT*8);
  float4* recN   = (float4*)alloc(((size_t)NTOT*2 + 32)*16);
  float*  srowA  = (float*) alloc((size_t)NTOT*4);
  float*  t1     = (float*) alloc(128*4);
  int*    nf1    = (int*)   alloc(256);
  int*    nf2    = (int*)   alloc(BG*4);
  int*    segU   = (int*)   alloc(BG*8*4);
  float*  ushG   = (float*) alloc((size_t)BG*HD*4);
  float*  AC1    = (float*) alloc((size_t)NSEG*256*4);
  float*  hgsum  = (float*) alloc((size_t)BG*HD*4);
  float*  t2     = (float*) alloc((size_t)BG*HD*4);
  float*  AC2    = (float*) alloc((size_t)BG*NSEG*256*4);

  hipMemsetAsync(hgsum, 0, (size_t)BG*HD*4, stream);
  hipMemsetAsync(segU,  0, (size_t)BG*8*4, stream);

  k_csr<<<BG+1, 1024, 0, stream>>>(ei, x, enc_w1, enc_b1, enc_w2,
                                   cnt, eoP, csrc, axsr, t1, AC1, nf1);

  k_pack<<<NTOT/256, 256, 0, stream>>>(axsr, eoP, cnt, t1, recN, srowA);

  k_enc_agg<<<1024, 256, 0, stream>>>(recN, csrc, (const float4*)AC1, enc_b2, nf1, hgsum);

  k_small<<<BG, 128, 0, stream>>>(hgsum, mu_w, mu_b, lv_w, lv_b, eps,
                                  zn_w, zn_b, dec_w1, dec_b1,
                                  out_mu, out_lv, out_z, t2, ushG, nf2);

  k_seg2<<<NTOT/256, 256, 0, stream>>>(t2, srowA, (float*)recN, segU);

  k_tab2rows<<<BG, 128, 0, stream>>>(ushG, dec_b1, dec_w2, segU, nf2, AC2);

  k_dec_agg<<<1024, 256, 0, stream>>>(recN, csrc, (const float4*)AC2,
                                      dec_b2, out_w, out_b, nf2, out_recon);
}

// Round 9
// 182.102 us; speedup vs baseline: 1.2209x; 1.0157x over previous
//
#include <hip/hip_runtime.h>
#include <math.h>

#define NTOT 262144   // total nodes
#define BG   64       // graphs
#define NNPG 4096     // nodes per graph
#define ET   1048576  // directed edges
#define EPG  16384    // edges per graph
#define HD   128
#define LD   64
#define NSEG 129
#define SLOTPG 28672  // max padded slots per graph (EPG + 3*NNPG)
#define SLOTCAP (BG*SLOTPG)
#define TN   256      // nodes per agg tile (one per thread in phase 1)

// ======== fused CSR build + ax/srow accumulation (1 block/graph, LDS) ======
// block BG runs tab1. Edge list is register-preloaded (8x int4/thread) so the
// count and place passes have 4-deep ILP and no global re-reads; block scan is
// a wave-shfl scan (2 barriers).
__global__ void __launch_bounds__(1024) k_csr(
    const int* __restrict__ ei, const float* __restrict__ x,
    const float* __restrict__ w1, const float* __restrict__ b1,
    const float* __restrict__ w2,
    int* __restrict__ cnt, int* __restrict__ off, int* __restrict__ csrc,
    float2* __restrict__ axsr,
    float* __restrict__ t1, float* __restrict__ AC1, int* __restrict__ nfp)
{
  __shared__ union {
    struct { int cur[NNPG]; float xs[NNPG]; float dinvs[NNPG];
             float axs[NNPG]; float s1s[NNPG]; int tsum[64]; } c;
    struct { float w2s[HD*HD]; float ts[128], ws[128], bs[128];
             int ks[128], jr[128]; } t;
  } u;
  int tid = threadIdx.x;

  if (blockIdx.x == BG){
    // ---------------- tab1 ----------------
    {
      const float4* src = (const float4*)w2;
      float4* dst = (float4*)u.t.w2s;
      for (int idx = tid; idx < HD*HD/4; idx += 1024) dst[idx] = src[idx];
    }
    if (tid < 128){
      float w = w1[tid], b = b1[tid];
      float t; int kind;
      if (w != 0.0f){ t = -b / w; kind = (w > 0.0f) ? 0 : 1; }
      else          { t = INFINITY; kind = 2; }
      u.t.ts[tid] = t; u.t.ks[tid] = kind; u.t.ws[tid] = w; u.t.bs[tid] = b;
      u.t.jr[tid] = -1;
    }
    __syncthreads();
    if (tid == 0){
      int c = 0;
      for (int q = 0; q < 128; q++) c += (u.t.ks[q] != 2) ? 1 : 0;
      nfp[0] = c;
    }
    if (tid < 128){
      int j = tid;
      float t = u.t.ts[j];
      int r = 0;
      for (int q = 0; q < 128; q++){
        if (u.t.ks[q] != 2){
          float tq = u.t.ts[q];
          if (tq < t || (tq == t && q < j)) r++;
        }
      }
      t1[j] = t;
      if (u.t.ks[j] != 2) u.t.jr[r] = j;
    }
    __syncthreads();
    if (tid < 128){
      int k = tid;
      float a = 0.f, c = 0.f;
      for (int q = 0; q < 128; q++){    // segment 0: kind1 all active
        int kd = u.t.ks[q];
        bool act = (kd == 1) || (kd == 2 && u.t.bs[q] > 0.0f);
        if (act){ float v = u.t.w2s[q*HD + k]; a = fmaf(u.t.ws[q], v, a); c = fmaf(u.t.bs[q], v, c); }
      }
      int base = (k>>2)*8 + (k&3);
      AC1[base] = a; AC1[base+4] = c;
      for (int s = 0; s < 128; s++){
        int q = u.t.jr[s];
        if (q >= 0){
          float sg = (u.t.ks[q] == 0) ? 1.f : -1.f;
          float v  = u.t.w2s[q*HD + k];
          a = fmaf(sg*u.t.ws[q], v, a);
          c = fmaf(sg*u.t.bs[q], v, c);
        }
        int o = (s+1)*256 + base;
        AC1[o] = a; AC1[o+4] = c;
      }
    }
    return;
  }

  // ---------------- CSR + ax/srow for graph g ----------------
  int g = blockIdx.x;
  int gbase = g*NNPG;
  const int4* srcs4 = (const int4*)(ei + g*EPG);
  const int4* dsts4 = (const int4*)(ei + ET + g*EPG);
  // preload ALL edges for this thread (loads overlap the LDS init below)
  int4 S0 = srcs4[0*1024 + tid], S1 = srcs4[1*1024 + tid];
  int4 S2 = srcs4[2*1024 + tid], S3 = srcs4[3*1024 + tid];
  int4 D0 = dsts4[0*1024 + tid], D1 = dsts4[1*1024 + tid];
  int4 D2 = dsts4[2*1024 + tid], D3 = dsts4[3*1024 + tid];
  #pragma unroll
  for (int k = tid; k < NNPG; k += 1024){
    u.c.cur[k] = 0; u.c.axs[k] = 0.f; u.c.s1s[k] = 0.f;
    u.c.xs[k] = x[gbase + k];
  }
  __syncthreads();
  // ---- count (4-deep ILP) ----
  #define CNT4(D_) { atomicAdd(&u.c.cur[D_.x - gbase], 1); atomicAdd(&u.c.cur[D_.y - gbase], 1); \
                     atomicAdd(&u.c.cur[D_.z - gbase], 1); atomicAdd(&u.c.cur[D_.w - gbase], 1); }
  CNT4(D0); CNT4(D1); CNT4(D2); CNT4(D3);
  #undef CNT4
  __syncthreads();
  int n0 = u.c.cur[4*tid+0], n1 = u.c.cur[4*tid+1];
  int n2 = u.c.cur[4*tid+2], n3 = u.c.cur[4*tid+3];
  float di0 = rsqrtf((float)n0 + 1.0f), di1 = rsqrtf((float)n1 + 1.0f);
  float di2 = rsqrtf((float)n2 + 1.0f), di3 = rsqrtf((float)n3 + 1.0f);
  u.c.dinvs[4*tid+0] = di0; u.c.dinvs[4*tid+1] = di1;
  u.c.dinvs[4*tid+2] = di2; u.c.dinvs[4*tid+3] = di3;
  int p0 = (n0+3)&~3, p1 = (n1+3)&~3, p2 = (n2+3)&~3, p3 = (n3+3)&~3;
  int tsum = p0+p1+p2+p3;
  // ---- wave-shfl block scan (2 barriers) ----
  int lane = tid & 63, wv = tid >> 6;
  int incl = tsum;
  #pragma unroll
  for (int dd = 1; dd < 64; dd <<= 1){
    int v = __shfl_up(incl, dd, 64);
    if (lane >= dd) incl += v;
  }
  if (lane == 63) u.c.tsum[wv] = incl;
  __syncthreads();
  if (tid < 64){
    int v = (tid < 16) ? u.c.tsum[tid] : 0;
    int inc2 = v;
    #pragma unroll
    for (int dd = 1; dd < 16; dd <<= 1){
      int t2 = __shfl_up(inc2, dd, 64);
      if (tid >= dd) inc2 += t2;
    }
    if (tid < 16) u.c.tsum[tid] = inc2 - v;   // exclusive wave base
  }
  __syncthreads();
  int tbase = u.c.tsum[wv] + incl - tsum;     // exclusive
  int sbase = g*SLOTPG;
  int o0 = tbase, o1 = o0+p0, o2 = o1+p1, o3 = o2+p2;
  int i0 = gbase + 4*tid;
  *(int4*)(cnt + i0) = make_int4(n0, n1, n2, n3);
  *(int4*)(off + i0) = make_int4(sbase+o0, sbase+o1, sbase+o2, sbase+o3);
  for (int s = n0; s < p0; s++) csrc[sbase+o0+s] = -1;
  for (int s = n1; s < p1; s++) csrc[sbase+o1+s] = -1;
  for (int s = n2; s < p2; s++) csrc[sbase+o2+s] = -1;
  for (int s = n3; s < p3; s++) csrc[sbase+o3+s] = -1;
  u.c.cur[4*tid+0] = o0; u.c.cur[4*tid+1] = o1;
  u.c.cur[4*tid+2] = o2; u.c.cur[4*tid+3] = o3;
  __syncthreads();
  // ---- place + ax/srow accumulate (registers only, 4-deep ILP) ----
  #define PLACE1(s_, d_) { int sl = (s_) - gbase, dl = (d_) - gbase; \
    float v_ = u.c.dinvs[sl]; float xv_ = u.c.xs[sl]; \
    int p_ = atomicAdd(&u.c.cur[dl], 1); \
    csrc[sbase + p_] = (s_); \
    atomicAdd(&u.c.axs[dl], v_*xv_); \
    atomicAdd(&u.c.s1s[dl], v_); }
  #define PLACE4(S_, D_) { PLACE1(S_.x, D_.x); PLACE1(S_.y, D_.y); PLACE1(S_.z, D_.z); PLACE1(S_.w, D_.w); }
  PLACE4(S0, D0); PLACE4(S1, D1); PLACE4(S2, D2); PLACE4(S3, D3);
  #undef PLACE4
  #undef PLACE1
  __syncthreads();
  float ax0 = di0 * (di0 * u.c.xs[4*tid+0] + u.c.axs[4*tid+0]);
  float ax1 = di1 * (di1 * u.c.xs[4*tid+1] + u.c.axs[4*tid+1]);
  float ax2 = di2 * (di2 * u.c.xs[4*tid+2] + u.c.axs[4*tid+2]);
  float ax3 = di3 * (di3 * u.c.xs[4*tid+3] + u.c.axs[4*tid+3]);
  float sr0 = di0 * (di0 + u.c.s1s[4*tid+0]);
  float sr1 = di1 * (di1 + u.c.s1s[4*tid+1]);
  float sr2 = di2 * (di2 + u.c.s1s[4*tid+2]);
  float sr3 = di3 * (di3 + u.c.s1s[4*tid+3]);
  float4* axsr4 = (float4*)axsr;
  int b4 = (gbase >> 1) + tid*2;
  axsr4[b4+0] = make_float4(ax0, sr0, ax1, sr1);
  axsr4[b4+1] = make_float4(ax2, sr2, ax3, sr3);
}

// ---- pack per-node records (gather-free): recN[2i]=(d, d*ax, d*srow, segE),
// recN[2i+1]=(eo,np,0,0); srowA for decoder segs
__global__ void k_pack(const float2* __restrict__ axsr,
                       const int* __restrict__ off, const int* __restrict__ cnt,
                       const float* __restrict__ t1,
                       float4* __restrict__ recN, float* __restrict__ srowA){
  __shared__ float ts[128];
  if (threadIdx.x < 128) ts[threadIdx.x] = t1[threadIdx.x];
  __syncthreads();
  int i = blockIdx.x*256 + threadIdx.x;
  int n = cnt[i], eo = off[i];
  float di = rsqrtf((float)n + 1.0f);
  float2 as = axsr[i];
  int sc = 0;
  for (int q = 0; q < 128; q++) sc += (ts[q] < as.x) ? 1 : 0;
  int np = (n + 3) & ~3;
  recN[2*i]   = make_float4(di, di*as.x, di*as.y, __int_as_float(sc));
  recN[2*i+1] = make_float4(__int_as_float(eo), __int_as_float(np), 0.f, 0.f);
  srowA[i] = as.y;
}

// ---------------- fused encoder GCN2 + relu + mean-pool ----------------
__global__ void __launch_bounds__(256) k_enc_agg(
    const float4* __restrict__ recN, const int* __restrict__ csrc,
    const float4* __restrict__ AC, const float* __restrict__ b2,
    const int* __restrict__ nfp, float* __restrict__ hgsum)
{
  __shared__ float4 sS[TN];
  __shared__ float4 sRA[TN];
  __shared__ int sFlag[TN];
  __shared__ float red[256*4];
  int bid = blockIdx.x, g = bid & 63, part = bid >> 6;   // 1024 blocks
  int tid = threadIdx.x, lane = tid & 31, nrow = tid >> 5;
  int base = g*NNPG + part*TN;
  int nf = nfp[0];
  {
    int i = base + tid;
    sRA[tid] = recN[2*i];
    float4 rB = recN[2*i+1];
    int eo = __float_as_int(rB.x), np = __float_as_int(rB.y);
    float swa=0.f, sw=0.f, swaN=0.f, swN=0.f;
    int flag = 0;
    for (int t = 0; t < np; t += 4){
      int4 ss = *(const int4*)(csrc + eo + t);
      #pragma unroll
      for (int uu = 0; uu < 4; uu++){
        int s = (uu==0)?ss.x:(uu==1)?ss.y:(uu==2)?ss.z:ss.w;
        if (s >= 0){
          float4 r = recN[2*s];
          int sb = __float_as_int(r.w);
          swa += r.y; sw += r.x;
          bool isN = (sb == nf) && (sb != 0);
          swaN += isN ? r.y : 0.f;
          swN  += isN ? r.x : 0.f;
          flag |= (sb != 0 && sb != nf) ? 1 : 0;
        }
      }
    }
    sS[tid] = make_float4(swa, sw, swaN, swN);
    sFlag[tid] = flag;
  }
  __syncthreads();
  const float4* q0 = AC + (size_t)lane*2;
  const float4* qn = AC + ((size_t)nf*32 + lane)*2;
  float4 A0 = q0[0], C0 = q0[1], An = qn[0], Cn = qn[1];
  float4 dA = make_float4(An.x-A0.x, An.y-A0.y, An.z-A0.z, An.w-A0.w);
  float4 dC = make_float4(Cn.x-C0.x, Cn.y-C0.y, Cn.z-C0.z, Cn.w-C0.w);
  float4 bb = ((const float4*)b2)[lane];
  float gx=0.f, gy=0.f, gz=0.f, gw=0.f;
  for (int it = 0; it < TN/8; ++it){
    int li = it*8 + nrow;
    int i = base + li;
    float4 rA = sRA[li];
    float accx, accy, accz, accw;
    if (sFlag[li]){              // rare slow path: full 32-wide recompute
      float4 rB = recN[2*i+1];
      int eo = __float_as_int(rB.x), np = __float_as_int(rB.y);
      float swa=0.f, sw=0.f, swaN=0.f, swN=0.f;
      float mx=0.f, my=0.f, mz=0.f, mw=0.f;
      for (int t = 0; t < np; ++t){
        int s = csrc[eo+t];
        if (s < 0) continue;
        float4 r = recN[2*s];
        int sb = __float_as_int(r.w);
        float v = r.y;
        swa += v; sw += r.x;
        bool isN = (sb == nf) && (sb != 0);
        swaN += isN ? v : 0.f; swN += isN ? r.x : 0.f;
        if (sb != 0 && sb != nf){
          const float4* qm = AC + ((size_t)sb*32 + lane)*2;
          float4 qa = qm[0], qc = qm[1];
          mx = fmaf(v, qa.x-A0.x, fmaf(r.x, qc.x-C0.x, mx));
          my = fmaf(v, qa.y-A0.y, fmaf(r.x, qc.y-C0.y, my));
          mz = fmaf(v, qa.z-A0.z, fmaf(r.x, qc.z-C0.z, mz));
          mw = fmaf(v, qa.w-A0.w, fmaf(r.x, qc.w-C0.w, mw));
        }
      }
      accx = fmaf(swa,A0.x, fmaf(swaN,dA.x, fmaf(sw,C0.x, fmaf(swN,dC.x, mx))));
      accy = fmaf(swa,A0.y, fmaf(swaN,dA.y, fmaf(sw,C0.y, fmaf(swN,dC.y, my))));
      accz = fmaf(swa,A0.z, fmaf(swaN,dA.z, fmaf(sw,C0.z, fmaf(swN,dC.z, mz))));
      accw = fmaf(swa,A0.w, fmaf(swaN,dA.w, fmaf(sw,C0.w, fmaf(swN,dC.w, mw))));
    } else {
      float4 s4 = sS[li];
      accx = fmaf(s4.x,A0.x, fmaf(s4.z,dA.x, fmaf(s4.y,C0.x, s4.w*dC.x)));
      accy = fmaf(s4.x,A0.y, fmaf(s4.z,dA.y, fmaf(s4.y,C0.y, s4.w*dC.y)));
      accz = fmaf(s4.x,A0.z, fmaf(s4.z,dA.z, fmaf(s4.y,C0.z, s4.w*dC.z)));
      accw = fmaf(s4.x,A0.w, fmaf(s4.z,dA.w, fmaf(s4.y,C0.w, s4.w*dC.w)));
    }
    int si = __float_as_int(rA.w);
    bool m0 = (si == 0);
    float4 sa, sc;
    sa.x = m0 ? A0.x : An.x; sa.y = m0 ? A0.y : An.y; sa.z = m0 ? A0.z : An.z; sa.w = m0 ? A0.w : An.w;
    sc.x = m0 ? C0.x : Cn.x; sc.y = m0 ? C0.y : Cn.y; sc.z = m0 ? C0.z : Cn.z; sc.w = m0 ? C0.w : Cn.w;
    if (si != 0 && si != nf){
      const float4* qs = AC + ((size_t)si*32 + lane)*2;
      sa = qs[0]; sc = qs[1];
    }
    float d = rA.x, d2 = d*d, ca = rA.y*d;
    gx += fmaxf(fmaf(d, accx, fmaf(ca, sa.x, d2*sc.x)) + bb.x, 0.f);
    gy += fmaxf(fmaf(d, accy, fmaf(ca, sa.y, d2*sc.y)) + bb.y, 0.f);
    gz += fmaxf(fmaf(d, accz, fmaf(ca, sa.z, d2*sc.z)) + bb.z, 0.f);
    gw += fmaxf(fmaf(d, accw, fmaf(ca, sa.w, d2*sc.w)) + bb.w, 0.f);
  }
  __syncthreads();
  red[tid*4+0] = gx; red[tid*4+1] = gy; red[tid*4+2] = gz; red[tid*4+3] = gw;
  __syncthreads();
  if (nrow == 0){
    float tx=0.f, ty=0.f, tz=0.f, tw=0.f;
    for (int r2 = 0; r2 < 8; r2++){
      int t2 = (r2*32 + lane)*4;
      tx += red[t2]; ty += red[t2+1]; tz += red[t2+2]; tw += red[t2+3];
    }
    atomicAdd(&hgsum[g*HD + lane*4 + 0], tx);
    atomicAdd(&hgsum[g*HD + lane*4 + 1], ty);
    atomicAdd(&hgsum[g*HD + lane*4 + 2], tz);
    atomicAdd(&hgsum[g*HD + lane*4 + 3], tw);
  }
}

// ------- per-graph dense chain (slim: no table build) -------
__global__ void __launch_bounds__(128) k_small(
    const float* __restrict__ hgsum,
    const float* __restrict__ mu_w, const float* __restrict__ mu_b,
    const float* __restrict__ lv_w, const float* __restrict__ lv_b,
    const float* __restrict__ eps,
    const float* __restrict__ zn_w, const float* __restrict__ zn_b,
    const float* __restrict__ dec_w1, const float* __restrict__ dec_b1,
    float* __restrict__ out_mu, float* __restrict__ out_lv, float* __restrict__ out_z,
    float* __restrict__ t2, float* __restrict__ ushG, int* __restrict__ nf2)
{
  int g = blockIdx.x, tid = threadIdx.x;
  __shared__ float hg[128], zsh[64], znsh[128];
  __shared__ int ks[128];
  hg[tid] = hgsum[g*HD + tid] * (1.0f/4096.0f);
  __syncthreads();
  if (tid < 64){
    int l = tid;
    float m = mu_b[l], v = lv_b[l];
    for (int k = 0; k < HD; k++){
      float hv = hg[k];
      m = fmaf(hv, mu_w[k*LD + l], m);
      v = fmaf(hv, lv_w[k*LD + l], v);
    }
    int o = g*LD + l;
    out_mu[o] = m; out_lv[o] = v;
    float zv = fmaf(expf(0.5f*v), eps[o], m);
    out_z[o] = zv; zsh[l] = zv;
  }
  __syncthreads();
  {
    int k = tid;
    float acc = zn_b[k];
    for (int l = 0; l < LD; l++) acc = fmaf(zsh[l], zn_w[l*HD + k], acc);
    znsh[k] = acc;
  }
  __syncthreads();
  float w;
  {
    int k = tid;
    float acc = 0.f;
    for (int j = 0; j < HD; j++) acc = fmaf(znsh[j], dec_w1[j*HD + k], acc);
    ushG[g*HD + k] = acc;
    w = acc;
  }
  float b = dec_b1[tid];
  float t; int kind;
  if (w != 0.0f){ t = -b / w; kind = (w > 0.0f) ? 0 : 1; }
  else          { t = INFINITY; kind = 2; }
  t2[g*HD + tid] = t; ks[tid] = kind;
  __syncthreads();
  if (tid == 0){
    int c = 0;
    for (int q = 0; q < 128; q++) c += (ks[q] != 2) ? 1 : 0;
    nf2[g] = c;
  }
}

// segD per node -> overwrite recN[2i].y (d*ax, dead after encoder) + used bitmap
__global__ void k_seg2(const float* __restrict__ t2, const float* __restrict__ srowA,
                       float* __restrict__ recNf, int* __restrict__ segUsed){
  __shared__ float ts[128];
  __shared__ int used[8];
  int tid = threadIdx.x;
  int i = blockIdx.x*256 + tid;
  int g = blockIdx.x >> 4;
  if (tid < 128) ts[tid] = t2[g*HD + tid];
  if (tid < 8) used[tid] = 0;
  __syncthreads();
  float a = srowA[i];
  int sc = 0;
  for (int q = 0; q < 128; q++) sc += (ts[q] < a) ? 1 : 0;
  recNf[(2*i)*4 + 1] = __int_as_float(sc);
  atomicOr(&used[sc>>5], 1u << (sc & 31));
  __syncthreads();
  if (tid < 8 && used[tid]) atomicOr(&segUsed[g*8 + tid], used[tid]);
}

// ---- build only the USED decoder table rows (plus rows 0 and nf) ----
__global__ void __launch_bounds__(128) k_tab2rows(
    const float* __restrict__ ushG, const float* __restrict__ dec_b1,
    const float* __restrict__ w2, const int* __restrict__ segUsed,
    const int* __restrict__ nf2, float* __restrict__ AC2)
{
  __shared__ float w2s[HD*HD];
  __shared__ float ws[128], bs[128], tsh[128];
  __shared__ int ks[128], rr[128];
  int g = blockIdx.x, j = threadIdx.x;
  {
    const float4* src = (const float4*)w2;
    float4* dst = (float4*)w2s;
    #pragma unroll
    for (int idx = 0; idx < HD*HD/4/128; idx++) dst[idx*128 + j] = src[idx*128 + j];
  }
  float w = ushG[g*HD + j], b = dec_b1[j];
  float t; int kind;
  if (w != 0.0f){ t = -b / w; kind = (w > 0.0f) ? 0 : 1; }
  else          { t = INFINITY; kind = 2; }
  ws[j] = w; bs[j] = b; tsh[j] = t; ks[j] = kind;
  __syncthreads();
  int r = 0;
  for (int q = 0; q < 128; q++){
    if (ks[q] != 2){
      float tq = tsh[q];
      if (tq < t || (tq == t && q < j)) r++;
    }
  }
  rr[j] = r;
  __syncthreads();
  int nf = nf2[g];
  float* ACg = AC2 + (size_t)g*NSEG*256;
  int base = (j>>2)*8 + (j&3);
  for (int wd = 0; wd < 5; wd++){
    unsigned m = (unsigned)segUsed[g*8 + wd];
    if (wd == 0) m |= 1u;
    if ((nf >> 5) == wd) m |= 1u << (nf & 31);
    while (m){
      int bit = __ffs(m) - 1;
      m &= m - 1;
      int s = wd*32 + bit;
      float a = 0.f, c = 0.f;
      #pragma unroll 8
      for (int q = 0; q < 128; q++){
        int kd = ks[q];
        bool act = (kd == 0) ? (rr[q] < s) : (kd == 1) ? (rr[q] >= s) : (bs[q] > 0.0f);
        float v = act ? w2s[q*HD + j] : 0.0f;
        a = fmaf(ws[q], v, a); c = fmaf(bs[q], v, c);
      }
      ACg[s*256 + base] = a; ACg[s*256 + base + 4] = c;
    }
  }
}

// ---------------- fused decoder GCN2 + relu + out-proj + tanh ----------------
// recN[2i] = (d, segD, d*srow, segE_unused)
__global__ void __launch_bounds__(256) k_dec_agg(
    const float4* __restrict__ recN, const int* __restrict__ csrc,
    const float4* __restrict__ AC2, const float* __restrict__ b2,
    const float* __restrict__ ow, const float* __restrict__ ob,
    const int* __restrict__ nf2, float* __restrict__ recon)
{
  __shared__ float4 sS[TN];
  __shared__ float4 sRA[TN];
  __shared__ int sFlag[TN];
  int bid = blockIdx.x, g = bid & 63, part = bid >> 6;
  int tid = threadIdx.x, lane = tid & 31, nrow = tid >> 5;
  int base = g*NNPG + part*TN;
  int nf = nf2[g];
  const float4* AC = AC2 + (size_t)g*NSEG*64;
  {
    int i = base + tid;
    sRA[tid] = recN[2*i];
    float4 rB = recN[2*i+1];
    int eo = __float_as_int(rB.x), np = __float_as_int(rB.y);
    float swa=0.f, sw=0.f, swaN=0.f, swN=0.f;
    int flag = 0;
    for (int t = 0; t < np; t += 4){
      int4 ss = *(const int4*)(csrc + eo + t);
      #pragma unroll
      for (int uu = 0; uu < 4; uu++){
        int s = (uu==0)?ss.x:(uu==1)?ss.y:(uu==2)?ss.z:ss.w;
        if (s >= 0){
          float4 r = recN[2*s];
          int sb = __float_as_int(r.y);
          swa += r.z; sw += r.x;
          bool isN = (sb == nf) && (sb != 0);
          swaN += isN ? r.z : 0.f;
          swN  += isN ? r.x : 0.f;
          flag |= (sb != 0 && sb != nf) ? 1 : 0;
        }
      }
    }
    sS[tid] = make_float4(swa, sw, swaN, swN);
    sFlag[tid] = flag;
  }
  __syncthreads();
  const float4* q0 = AC + (size_t)lane*2;
  const float4* qn = AC + ((size_t)nf*32 + lane)*2;
  float4 A0 = q0[0], C0 = q0[1], An = qn[0], Cn = qn[1];
  float4 dA = make_float4(An.x-A0.x, An.y-A0.y, An.z-A0.z, An.w-A0.w);
  float4 dC = make_float4(Cn.x-C0.x, Cn.y-C0.y, Cn.z-C0.z, Cn.w-C0.w);
  float4 bb  = ((const float4*)b2)[lane];
  float4 owv = ((const float4*)ow)[lane];
  float obv = ob[0];
  for (int it = 0; it < TN/8; ++it){
    int li = it*8 + nrow;
    int i = base + li;
    float4 rA = sRA[li];
    float accx, accy, accz, accw;
    if (sFlag[li]){              // rare slow path
      float4 rB = recN[2*i+1];
      int eo = __float_as_int(rB.x), np = __float_as_int(rB.y);
      float swa=0.f, sw=0.f, swaN=0.f, swN=0.f;
      float mx=0.f, my=0.f, mz=0.f, mw=0.f;
      for (int t = 0; t < np; ++t){
        int s = csrc[eo+t];
        if (s < 0) continue;
        float4 r = recN[2*s];
        int sb = __float_as_int(r.y);
        float v = r.z;
        swa += v; sw += r.x;
        bool isN = (sb == nf) && (sb != 0);
        swaN += isN ? v : 0.f; swN += isN ? r.x : 0.f;
        if (sb != 0 && sb != nf){
          const float4* qm = AC + ((size_t)sb*32 + lane)*2;
          float4 qa = qm[0], qc = qm[1];
          mx = fmaf(v, qa.x-A0.x, fmaf(r.x, qc.x-C0.x, mx));
          my = fmaf(v, qa.y-A0.y, fmaf(r.x, qc.y-C0.y, my));
          mz = fmaf(v, qa.z-A0.z, fmaf(r.x, qc.z-C0.z, mz));
          mw = fmaf(v, qa.w-A0.w, fmaf(r.x, qc.w-C0.w, mw));
        }
      }
      accx = fmaf(swa,A0.x, fmaf(swaN,dA.x, fmaf(sw,C0.x, fmaf(swN,dC.x, mx))));
      accy = fmaf(swa,A0.y, fmaf(swaN,dA.y, fmaf(sw,C0.y, fmaf(swN,dC.y, my))));
      accz = fmaf(swa,A0.z, fmaf(swaN,dA.z, fmaf(sw,C0.z, fmaf(swN,dC.z, mz))));
      accw = fmaf(swa,A0.w, fmaf(swaN,dA.w, fmaf(sw,C0.w, fmaf(swN,dC.w, mw))));
    } else {
      float4 s4 = sS[li];
      accx = fmaf(s4.x,A0.x, fmaf(s4.z,dA.x, fmaf(s4.y,C0.x, s4.w*dC.x)));
      accy = fmaf(s4.x,A0.y, fmaf(s4.z,dA.y, fmaf(s4.y,C0.y, s4.w*dC.y)));
      accz = fmaf(s4.x,A0.z, fmaf(s4.z,dA.z, fmaf(s4.y,C0.z, s4.w*dC.z)));
      accw = fmaf(s4.x,A0.w, fmaf(s4.z,dA.w, fmaf(s4.y,C0.w, s4.w*dC.w)));
    }
    int si = __float_as_int(rA.y);
    bool m0 = (si == 0);
    float4 sa, sc;
    sa.x = m0 ? A0.x : An.x; sa.y = m0 ? A0.y : An.y; sa.z = m0 ? A0.z : An.z; sa.w = m0 ? A0.w : An.w;
    sc.x = m0 ? C0.x : Cn.x; sc.y = m0 ? C0.y : Cn.y; sc.z = m0 ? C0.z : Cn.z; sc.w = m0 ? C0.w : Cn.w;
    if (si != 0 && si != nf){
      const float4* qs = AC + ((size_t)si*32 + lane)*2;
      sa = qs[0]; sc = qs[1];
    }
    float d = rA.x, d2 = d*d, ca = rA.z*d;
    float hx = fmaxf(fmaf(d, accx, fmaf(ca, sa.x, d2*sc.x)) + bb.x, 0.f);
    float hy = fmaxf(fmaf(d, accy, fmaf(ca, sa.y, d2*sc.y)) + bb.y, 0.f);
    float hz = fmaxf(fmaf(d, accz, fmaf(ca, sa.z, d2*sc.z)) + bb.z, 0.f);
    float hw = fmaxf(fmaf(d, accw, fmaf(ca, sa.w, d2*sc.w)) + bb.w, 0.f);
    float dsum = hx*owv.x + hy*owv.y + hz*owv.z + hw*owv.w;
    for (int o2 = 16; o2 > 0; o2 >>= 1) dsum += __shfl_down(dsum, o2, 32);
    if (lane == 0) recon[i] = tanhf(dsum + obv);
  }
}

// ---------------- launch ----------------
extern "C" void kernel_launch(void* const* d_in, const int* in_sizes, int n_in,
                              void* d_out, int out_size, void* d_ws, size_t ws_size,
                              hipStream_t stream){
  (void)in_sizes; (void)n_in; (void)out_size; (void)ws_size;
  const float* x      = (const float*)d_in[0];
  const float* eps    = (const float*)d_in[1];
  const float* enc_w1 = (const float*)d_in[2];
  const float* enc_b1 = (const float*)d_in[3];
  const float* enc_w2 = (const float*)d_in[4];
  const float* enc_b2 = (const float*)d_in[5];
  const float* mu_w   = (const float*)d_in[6];
  const float* mu_b   = (const float*)d_in[7];
  const float* lv_w   = (const float*)d_in[8];
  const float* lv_b   = (const float*)d_in[9];
  const float* zn_w   = (const float*)d_in[10];
  const float* zn_b   = (const float*)d_in[11];
  const float* dec_w1 = (const float*)d_in[12];
  const float* dec_b1 = (const float*)d_in[13];
  const float* dec_w2 = (const float*)d_in[14];
  const float* dec_b2 = (const float*)d_in[15];
  const float* out_w  = (const float*)d_in[16];
  const float* out_b  = (const float*)d_in[17];
  const int*   ei     = (const int*)d_in[18];

  float* out       = (float*)d_out;
  float* out_recon = out;
  float* out_mu    = out + NTOT;
  float* out_lv    = out_mu + BG*LD;
  float* out_z     = out_lv + BG*LD;

  char* w = (char*)d_ws;
  size_t off_b = 0;
  auto alloc = [&](size_t bytes)->void*{
    void* p = w + off_b;
    off_b += (bytes + 255) & ~(size_t)255;
    return p;
  };
  int*    cnt    = (int*)   alloc((size_t)NTOT*4);
  int*    eoP    = (int*)   alloc((size_t)NTOT*4);
  int*    csrc   = (int*)   alloc((size_t)SLOTCAP*4);
  float2* axsr   = (float2*)alloc((size_t)NTOT*8);
  float4* recN   = (float4*)alloc(((size_t)NTOT*2 + 32)*16);
  float*  srowA  = (float*) alloc((size_t)NTOT*4);
  float*  t1     = (float*) alloc(128*4);
  int*    nf1    = (int*)   alloc(256);
  int*    nf2    = (int*)   alloc(BG*4);
  int*    segU   = (int*)   alloc(BG*8*4);
  float*  ushG   = (float*) alloc((size_t)BG*HD*4);
  float*  AC1    = (float*) alloc((size_t)NSEG*256*4);
  float*  hgsum  = (float*) alloc((size_t)BG*HD*4);
  float*  t2     = (float*) alloc((size_t)BG*HD*4);
  float*  AC2    = (float*) alloc((size_t)BG*NSEG*256*4);

  hipMemsetAsync(hgsum, 0, (size_t)BG*HD*4, stream);
  hipMemsetAsync(segU,  0, (size_t)BG*8*4, stream);

  k_csr<<<BG+1, 1024, 0, stream>>>(ei, x, enc_w1, enc_b1, enc_w2,
                                   cnt, eoP, csrc, axsr, t1, AC1, nf1);

  k_pack<<<NTOT/256, 256, 0, stream>>>(axsr, eoP, cnt, t1, recN, srowA);

  k_enc_agg<<<1024, 256, 0, stream>>>(recN, csrc, (const float4*)AC1, enc_b2, nf1, hgsum);

  k_small<<<BG, 128, 0, stream>>>(hgsum, mu_w, mu_b, lv_w, lv_b, eps,
                                  zn_w, zn_b, dec_w1, dec_b1,
                                  out_mu, out_lv, out_z, t2, ushG, nf2);

  k_seg2<<<NTOT/256, 256, 0, stream>>>(t2, srowA, (float*)recN, segU);

  k_tab2rows<<<BG, 128, 0, stream>>>(ushG, dec_b1, dec_w2, segU, nf2, AC2);

  k_dec_agg<<<1024, 256, 0, stream>>>(recN, csrc, (const float4*)AC2,
                                      dec_b2, out_w, out_b, nf2, out_recon);
}